// Round 1
// baseline (679.930 us; speedup 1.0000x reference)
//
#include <hip/hip_runtime.h>
#include <hip/hip_bf16.h>
#include <math.h>

// Problem constants
#define FPD 96      // frame size
#define DPD 28      // digit/kernel size
#define CPD 69      // FPD - DPD + 1
#define NPD 4761    // CPD*CPD
#define KKC 3       // K iterations
#define SBN 256     // S*B images
#define TT 8        // T
#define HD 512      // H
#define ZDD 2

#define FRSTRIDE 97            // padded LDS row stride for frame
#define SPLITK 8
#define KCHUNK 596             // ceil(4761/8)

// ---------------------------------------------------------------------------
// K0: frame_left[ib][p] = frames[ib][timestep][p]   (timestep read on device)
__global__ __launch_bounds__(256) void init_frame_kernel(
    const float4* __restrict__ frames, const int* __restrict__ tsp,
    float4* __restrict__ frameL)
{
    int i = blockIdx.x * 256 + threadIdx.x;     // 589824 float4s total
    int t = *tsp;
    int ib = i / 2304;                          // 9216/4 float4 per image
    int rem = i - ib * 2304;
    frameL[i] = frames[(ib * TT + t) * 2304 + rem];
}

// ---------------------------------------------------------------------------
// K1: depthwise valid conv (96x96 * 28x28 -> 69x69) + softmax-exp (unnormalized)
// One block per image. Frame, kernel, conv results all in LDS.
__global__ __launch_bounds__(256) void conv_softmax_kernel(
    const float* __restrict__ frameL, const float* __restrict__ conv_kernel,
    float* __restrict__ e_buf, float* __restrict__ inv_denom, int k)
{
    __shared__ float fr[96 * FRSTRIDE + 8];   // padded rows
    __shared__ float kr[DPD * DPD];
    __shared__ float cv[NPD];
    __shared__ float red[64];

    const int t = threadIdx.x;
    const int ib = blockIdx.x;

    // load frame (row-padded)
    const float* src = frameL + (size_t)ib * 9216;
    for (int i = t; i < 9216; i += 256) {
        int r = i / 96;
        int c = i - r * 96;
        fr[r * FRSTRIDE + c] = src[i];
    }
    // zero padding column + tail (read by discarded lanes only, keep finite)
    for (int i = t; i < 96 + 8; i += 256) {
        if (i < 96) fr[i * FRSTRIDE + 96] = 0.f;
        else        fr[96 * FRSTRIDE + (i - 96)] = 0.f;
    }
    const float* ks = conv_kernel + ((size_t)ib * KKC + k) * (DPD * DPD);
    for (int i = t; i < DPD * DPD; i += 256) kr[i] = ks[i];
    __syncthreads();

    // 69 rows x 9 tiles of 8 outputs (last tile partially valid)
    for (int tile = t; tile < 69 * 9; tile += 256) {
        int oy  = tile / 9;
        int ox0 = (tile - oy * 9) * 8;
        float acc[8] = {0.f,0.f,0.f,0.f,0.f,0.f,0.f,0.f};
        for (int dy = 0; dy < DPD; ++dy) {
            const float* frow = &fr[(oy + dy) * FRSTRIDE + ox0];
            const float* krow = &kr[dy * DPD];
            float w[8];
            #pragma unroll
            for (int j = 0; j < 7; ++j) w[j] = frow[j];
            #pragma unroll
            for (int dx = 0; dx < DPD; ++dx) {
                w[7] = frow[dx + 7];
                float kv = krow[dx];
                #pragma unroll
                for (int j = 0; j < 8; ++j) acc[j] = fmaf(w[j], kv, acc[j]);
                #pragma unroll
                for (int j = 0; j < 7; ++j) w[j] = w[j + 1];
            }
        }
        int base = oy * CPD + ox0;
        #pragma unroll
        for (int j = 0; j < 8; ++j)
            if (ox0 + j < CPD) cv[base + j] = acc[j];
    }
    __syncthreads();

    // block max
    float m = -INFINITY;
    for (int i = t; i < NPD; i += 256) m = fmaxf(m, cv[i]);
    #pragma unroll
    for (int off = 32; off > 0; off >>= 1) m = fmaxf(m, __shfl_down(m, off, 64));
    int lane = t & 63, wid = t >> 6;
    if (lane == 0) red[wid] = m;
    __syncthreads();
    m = fmaxf(fmaxf(red[0], red[1]), fmaxf(red[2], red[3]));

    // exp + sum
    float s = 0.f;
    float* eo = e_buf + (size_t)ib * NPD;
    for (int i = t; i < NPD; i += 256) {
        float ev = __expf(cv[i] - m);
        eo[i] = ev;
        s += ev;
    }
    #pragma unroll
    for (int off = 32; off > 0; off >>= 1) s += __shfl_down(s, off, 64);
    if (lane == 0) red[8 + wid] = s;
    __syncthreads();
    if (t == 0) {
        float tot = red[8] + red[9] + red[10] + red[11];
        inv_denom[ib] = 1.0f / tot;
    }
}

// ---------------------------------------------------------------------------
// K2: Cpart[bz] += E(256x4761) @ W1(4761x512), split-K, 64x64 tiles
__global__ __launch_bounds__(256) void gemm1_kernel(
    const float* __restrict__ E, const float* __restrict__ W1,
    float* __restrict__ Cpart)
{
    __shared__ __align__(16) float As[16][64];   // [kk][m]
    __shared__ __align__(16) float Bs[16][64];   // [kk][n]

    const int t  = threadIdx.x;
    const int m0 = blockIdx.x * 64;   // 4
    const int n0 = blockIdx.y * 64;   // 8
    const int bz = blockIdx.z;        // 8
    const int k0 = bz * KCHUNK;
    const int k1 = min(NPD, k0 + KCHUNK);

    const int tx = t & 15, ty = t >> 4;
    float acc[4][4] = {};

    const int am = t >> 2;            // 0..63 (m within tile)
    const int ak = (t & 3) * 4;       // 0,4,8,12
    const int bk = t >> 4;            // 0..15
    const int bn = (t & 15) * 4;      // 0..60

    for (int kk0 = k0; kk0 < k1; kk0 += 16) {
        // A tile: E[(m0+am)][kk0+ak+j]
        const float* arow = E + (size_t)(m0 + am) * NPD + kk0 + ak;
        #pragma unroll
        for (int j = 0; j < 4; ++j) {
            float v = (kk0 + ak + j < k1) ? arow[j] : 0.f;
            As[ak + j][am] = v;
        }
        // B tile: W1[(kk0+bk)][n0+bn..+3]
        float4 bv = make_float4(0.f, 0.f, 0.f, 0.f);
        if (kk0 + bk < k1)
            bv = *reinterpret_cast<const float4*>(W1 + (size_t)(kk0 + bk) * HD + n0 + bn);
        *reinterpret_cast<float4*>(&Bs[bk][bn]) = bv;
        __syncthreads();

        #pragma unroll
        for (int kk = 0; kk < 16; ++kk) {
            float4 av = *reinterpret_cast<const float4*>(&As[kk][ty * 4]);
            float4 bvv = *reinterpret_cast<const float4*>(&Bs[kk][tx * 4]);
            float a_[4] = {av.x, av.y, av.z, av.w};
            float b_[4] = {bvv.x, bvv.y, bvv.z, bvv.w};
            #pragma unroll
            for (int i = 0; i < 4; ++i)
                #pragma unroll
                for (int j = 0; j < 4; ++j)
                    acc[i][j] = fmaf(a_[i], b_[j], acc[i][j]);
        }
        __syncthreads();
    }

    #pragma unroll
    for (int i = 0; i < 4; ++i) {
        float4 v = make_float4(acc[i][0], acc[i][1], acc[i][2], acc[i][3]);
        *reinterpret_cast<float4*>(
            Cpart + ((size_t)bz * SBN + m0 + ty * 4 + i) * HD + n0 + tx * 4) = v;
    }
}

// ---------------------------------------------------------------------------
// K3: h = relu(sum(Cpart)*inv_denom + b1); two MLP heads; write mean/std/z
// 64 blocks x 4 images each.
__global__ __launch_bounds__(256) void mlp_kernel(
    const float* __restrict__ Cpart, const float* __restrict__ inv_denom,
    const float* __restrict__ b1,
    const float* __restrict__ Wm1, const float* __restrict__ bm1,
    const float* __restrict__ Wm2, const float* __restrict__ bm2,
    const float* __restrict__ Ws1, const float* __restrict__ bs1,
    const float* __restrict__ Ws2, const float* __restrict__ bs2,
    const float* __restrict__ eps, float* __restrict__ out,
    float* __restrict__ z_cur, int k)
{
    __shared__ float hsh[4][HD];
    __shared__ float hm[4][256];
    __shared__ float hs[4][256];
    __shared__ float res_sh[4][2][2];

    const int t = threadIdx.x;
    const int ib0 = blockIdx.x * 4;

    // h rows for 4 images
    for (int q = 0; q < 4; ++q) {
        int ib = ib0 + q;
        float idn = inv_denom[ib];
        for (int n = t; n < HD; n += 256) {
            float s = 0.f;
            #pragma unroll
            for (int z = 0; z < SPLITK; ++z)
                s += Cpart[((size_t)z * SBN + ib) * HD + n];
            hsh[q][n] = fmaxf(fmaf(s, idn, b1[n]), 0.f);
        }
    }
    __syncthreads();

    // hidden layer of both heads: thread t -> column t (0..255)
    {
        float am[4] = {0.f,0.f,0.f,0.f};
        float as_[4] = {0.f,0.f,0.f,0.f};
        for (int i = 0; i < HD; ++i) {
            float wm = Wm1[(size_t)i * 256 + t];
            float ws = Ws1[(size_t)i * 256 + t];
            #pragma unroll
            for (int q = 0; q < 4; ++q) {
                am[q]  = fmaf(hsh[q][i], wm, am[q]);
                as_[q] = fmaf(hsh[q][i], ws, as_[q]);
            }
        }
        float bmv = bm1[t], bsv = bs1[t];
        #pragma unroll
        for (int q = 0; q < 4; ++q) {
            hm[q][t] = fmaxf(am[q] + bmv, 0.f);
            hs[q][t] = fmaxf(as_[q] + bsv, 0.f);
        }
    }
    __syncthreads();

    // output layer: 16 workers = 4 images x 2 zd x {mean,std}
    if (t < 16) {
        int q = t >> 2, zd = (t >> 1) & 1, which = t & 1;
        const float* W2 = which ? Ws2 : Wm2;
        const float* h2 = which ? hs[q] : hm[q];
        float acc = 0.f;
        for (int i = 0; i < 256; ++i) acc = fmaf(h2[i], W2[(size_t)i * 2 + zd], acc);
        float res = which ? __expf(acc + bs2[zd]) : tanhf(acc + bm2[zd]);
        res_sh[q][zd][which] = res;
    }
    __syncthreads();
    if (t < 8) {
        int q = t >> 1, zd = t & 1;
        int ib = ib0 + q;
        float mean = res_sh[q][zd][0];
        float stdv = res_sh[q][zd][1];
        float ev = eps[(size_t)ib * (KKC * ZDD) + k * ZDD + zd];
        float z = fmaf(stdv, ev, mean);
        int oidx = ib * (KKC * ZDD) + k * ZDD + zd;
        out[oidx]                  = mean;   // q_mean
        out[1536 + oidx]           = stdv;   // q_std
        out[3072 + oidx]           = z;      // z_where
        z_cur[ib * 2 + zd] = z;
    }
}

// ---------------------------------------------------------------------------
// K4: frame_left -= place_digit(conv_kernel[:,:,k], z)   (bilinear, zero pad)
__global__ __launch_bounds__(256) void recon_kernel(
    float* __restrict__ frameL, const float* __restrict__ conv_kernel,
    const float* __restrict__ z_cur, int k)
{
    __shared__ float dg[DPD * DPD];
    const int t = threadIdx.x, ib = blockIdx.x;
    const float zx = z_cur[ib * 2 + 0];
    const float zy = z_cur[ib * 2 + 1];
    const float* ks = conv_kernel + ((size_t)ib * KKC + k) * (DPD * DPD);
    for (int i = t; i < DPD * DPD; i += 256) dg[i] = ks[i];
    __syncthreads();

    const float scale = (float)FPD / (float)DPD;
    for (int p = t; p < 9216; p += 256) {
        int i = p / 96;
        int j = p - i * 96;
        float oci = (2.f * i + 1.f) / 96.f - 1.f;
        float ocj = (2.f * j + 1.f) / 96.f - 1.f;
        float py = ((scale * (oci - zy) + 1.f) * 28.f - 1.f) * 0.5f;
        float px = ((scale * (ocj - zx) + 1.f) * 28.f - 1.f) * 0.5f;
        float py0f = floorf(py), px0f = floorf(px);
        float fy = py - py0f, fx = px - px0f;
        int y0 = (int)py0f, x0 = (int)px0f;
        int y1 = y0 + 1, x1 = x0 + 1;
        float wy0 = (y0 >= 0 && y0 < DPD) ? 1.f - fy : 0.f;
        float wy1 = (y1 >= 0 && y1 < DPD) ? fy : 0.f;
        float wx0 = (x0 >= 0 && x0 < DPD) ? 1.f - fx : 0.f;
        float wx1 = (x1 >= 0 && x1 < DPD) ? fx : 0.f;
        int y0c = min(max(y0, 0), DPD - 1), y1c = min(max(y1, 0), DPD - 1);
        int x0c = min(max(x0, 0), DPD - 1), x1c = min(max(x1, 0), DPD - 1);
        float tmp0 = wy0 * dg[y0c * DPD + x0c] + wy1 * dg[y1c * DPD + x0c];
        float tmp1 = wy0 * dg[y0c * DPD + x1c] + wy1 * dg[y1c * DPD + x1c];
        float recon = wx0 * tmp0 + wx1 * tmp1;
        frameL[(size_t)ib * 9216 + p] -= recon;
    }
}

// ---------------------------------------------------------------------------
extern "C" void kernel_launch(void* const* d_in, const int* in_sizes, int n_in,
                              void* d_out, int out_size, void* d_ws, size_t ws_size,
                              hipStream_t stream)
{
    const float* frames = (const float*)d_in[0];
    const float* ck     = (const float*)d_in[1];
    const float* eps    = (const float*)d_in[2];
    const float* W1     = (const float*)d_in[3];
    const float* b1     = (const float*)d_in[4];
    const float* Wm1    = (const float*)d_in[5];
    const float* bm1    = (const float*)d_in[6];
    const float* Wm2    = (const float*)d_in[7];
    const float* bm2    = (const float*)d_in[8];
    const float* Ws1    = (const float*)d_in[9];
    const float* bs1    = (const float*)d_in[10];
    const float* Ws2    = (const float*)d_in[11];
    const float* bs2    = (const float*)d_in[12];
    const int*   tsp    = (const int*)d_in[13];
    float* out = (float*)d_out;

    float* frameL  = (float*)d_ws;                 // 256*9216
    float* e_buf   = frameL + 2359296;             // 256*4761
    float* inv_den = e_buf + 1218816;              // 256
    float* Cpart   = inv_den + 256;                // 8*256*512
    float* z_cur   = Cpart + 1048576;              // 512

    init_frame_kernel<<<2304, 256, 0, stream>>>(
        (const float4*)frames, tsp, (float4*)frameL);

    for (int k = 0; k < KKC; ++k) {
        conv_softmax_kernel<<<256, 256, 0, stream>>>(frameL, ck, e_buf, inv_den, k);
        gemm1_kernel<<<dim3(4, 8, 8), 256, 0, stream>>>(e_buf, W1, Cpart);
        mlp_kernel<<<64, 256, 0, stream>>>(Cpart, inv_den, b1,
                                           Wm1, bm1, Wm2, bm2,
                                           Ws1, bs1, Ws2, bs2,
                                           eps, out, z_cur, k);
        if (k < KKC - 1)
            recon_kernel<<<256, 256, 0, stream>>>(frameL, ck, z_cur, k);
    }
}

// Round 2
// 492.345 us; speedup vs baseline: 1.3810x; 1.3810x over previous
//
#include <hip/hip_runtime.h>
#include <hip/hip_bf16.h>
#include <math.h>

// Problem constants
#define FPD 96      // frame size
#define DPD 28      // digit/kernel size
#define CPD 69      // FPD - DPD + 1
#define NPD 4761    // CPD*CPD
#define KKC 3       // K iterations
#define SBN 256     // S*B images
#define TT 8        // T
#define HD 512      // H
#define ZDD 2
#define KPAD 4768   // 149*32, padded K for MFMA GEMM

#define SPLITK 8

typedef __attribute__((ext_vector_type(8))) short bf16x8;
typedef __attribute__((ext_vector_type(4))) float f32x4;

// ---------------------------------------------------------------------------
// K0: frame_left[ib][p] = frames[ib][timestep][p]   (timestep read on device)
__global__ __launch_bounds__(256) void init_frame_kernel(
    const float4* __restrict__ frames, const int* __restrict__ tsp,
    float4* __restrict__ frameL)
{
    int i = blockIdx.x * 256 + threadIdx.x;     // 589824 float4s total
    int t = *tsp;
    int ib = i / 2304;                          // 9216/4 float4 per image
    int rem = i - ib * 2304;
    frameL[i] = frames[(ib * TT + t) * 2304 + rem];
}

// ---------------------------------------------------------------------------
// K0b: W1T[n][k] = bf16(W1[k][n]), k padded to KPAD with zeros. Once per launch.
__global__ __launch_bounds__(256) void w1t_kernel(
    const float* __restrict__ W1, ushort* __restrict__ W1T)
{
    __shared__ ushort tile[64][65];
    const int k0 = blockIdx.x * 64;    // 75 blocks covers 4800 >= KPAD
    const int n0 = blockIdx.y * 64;    // 8 blocks
    const int t = threadIdx.x;
    const int ln = t & 63;
    const int lr = t >> 6;             // 0..3

    #pragma unroll
    for (int i = 0; i < 16; ++i) {
        int kk = k0 + lr + i * 4;
        float v = (kk < NPD) ? W1[(size_t)kk * HD + n0 + ln] : 0.f;
        __hip_bfloat16 h = __float2bfloat16(v);
        tile[lr + i * 4][ln] = *reinterpret_cast<ushort*>(&h);
    }
    __syncthreads();
    #pragma unroll
    for (int i = 0; i < 16; ++i) {
        int nn = lr + i * 4;
        int kk = k0 + ln;
        if (kk < KPAD)
            W1T[(size_t)(n0 + nn) * KPAD + kk] = tile[ln][nn];
    }
}

// ---------------------------------------------------------------------------
// K1: depthwise valid conv (96x96 * 28x28 -> 69x69) + softmax-exp (bf16, unnormalized)
// One block (1024 threads) per image.
__global__ __launch_bounds__(1024) void conv_softmax_kernel(
    const float* __restrict__ frameL, const float* __restrict__ conv_kernel,
    ushort* __restrict__ e_buf, float* __restrict__ inv_denom, int k)
{
    __shared__ float fr[96 * 97 + 8];
    __shared__ __align__(16) float kr[DPD * DPD];
    __shared__ float cv[NPD];
    __shared__ float red[32];

    const int t = threadIdx.x;
    const int ib = blockIdx.x;

    const float* src = frameL + (size_t)ib * 9216;
    for (int i = t; i < 9216; i += 1024) {
        int r = i / 96;
        int c = i - r * 96;
        fr[r * 97 + c] = src[i];
    }
    for (int i = t; i < 96 + 8; i += 1024) {
        if (i < 96) fr[i * 97 + 96] = 0.f;
        else        fr[96 * 97 + (i - 96)] = 0.f;
    }
    const float* ks = conv_kernel + ((size_t)ib * KKC + k) * (DPD * DPD);
    if (t < DPD * DPD) kr[t] = ks[t];
    for (int i = t; i < NPD; i += 1024) cv[i] = 0.f;
    __syncthreads();

    // tasks: 69 oy x 9 ox-tiles(8 wide) x 4 dy-quarters(7 rows) = 2484
    for (int task = t; task < 2484; task += 1024) {
        int q   = task / 621;
        int rem = task - q * 621;
        int oy  = rem / 9;
        int ox0 = (rem - oy * 9) * 8;
        int dy0 = q * 7;
        float acc[8] = {0.f,0.f,0.f,0.f,0.f,0.f,0.f,0.f};
        for (int dy = dy0; dy < dy0 + 7; ++dy) {
            const float* frow = &fr[(oy + dy) * 97 + ox0];
            const float* krow = &kr[dy * DPD];
            float c0[4], c1[4], c2[4];
            #pragma unroll
            for (int i = 0; i < 4; ++i) c0[i] = frow[i];
            #pragma unroll
            for (int i = 0; i < 4; ++i) c1[i] = frow[4 + i];
            #pragma unroll
            for (int dx = 0; dx < 28; dx += 4) {
                #pragma unroll
                for (int i = 0; i < 4; ++i) c2[i] = frow[dx + 8 + i];
                float4 kv = *(const float4*)&krow[dx];
                float kk4[4] = {kv.x, kv.y, kv.z, kv.w};
                float w[12];
                #pragma unroll
                for (int i = 0; i < 4; ++i) { w[i] = c0[i]; w[4+i] = c1[i]; w[8+i] = c2[i]; }
                #pragma unroll
                for (int i = 0; i < 4; ++i)
                    #pragma unroll
                    for (int j = 0; j < 8; ++j)
                        acc[j] = fmaf(w[i + j], kk4[i], acc[j]);
                #pragma unroll
                for (int i = 0; i < 4; ++i) { c0[i] = c1[i]; c1[i] = c2[i]; }
            }
        }
        int base = oy * CPD + ox0;
        #pragma unroll
        for (int j = 0; j < 8; ++j)
            if (ox0 + j < CPD) atomicAdd(&cv[base + j], acc[j]);
    }
    __syncthreads();

    // block max (16 waves)
    float m = -INFINITY;
    for (int i = t; i < NPD; i += 1024) m = fmaxf(m, cv[i]);
    #pragma unroll
    for (int off = 32; off > 0; off >>= 1) m = fmaxf(m, __shfl_down(m, off, 64));
    int lane = t & 63, wid = t >> 6;
    if (lane == 0) red[wid] = m;
    __syncthreads();
    m = red[0];
    #pragma unroll
    for (int i = 1; i < 16; ++i) m = fmaxf(m, red[i]);

    // exp (bf16 out) + sum
    float s = 0.f;
    ushort* eo = e_buf + (size_t)ib * KPAD;
    for (int i = t; i < NPD; i += 1024) {
        float ev = __expf(cv[i] - m);
        __hip_bfloat16 h = __float2bfloat16(ev);
        eo[i] = *reinterpret_cast<ushort*>(&h);
        s += ev;
    }
    #pragma unroll
    for (int off = 32; off > 0; off >>= 1) s += __shfl_down(s, off, 64);
    if (lane == 0) red[16 + wid] = s;
    __syncthreads();
    if (t == 0) {
        float tot = 0.f;
        #pragma unroll
        for (int i = 0; i < 16; ++i) tot += red[16 + i];
        inv_denom[ib] = 1.0f / tot;
    }
    if (t < KPAD - NPD) eo[NPD + t] = 0;   // zero k-padding
}

// ---------------------------------------------------------------------------
// K2: Cpart[z] = E(256xKPAD bf16) @ W1T^T (KPADx512 bf16), split-K=8, MFMA
// Block tile 64(m) x 64(n); 4 waves, wave w: m rows [w*16,w*16+16), 4 n-tiles.
__global__ __launch_bounds__(256) void gemm1_mfma(
    const ushort* __restrict__ E, const ushort* __restrict__ W1T,
    float* __restrict__ Cpart)
{
    __shared__ __align__(16) ushort As[64][56];   // [m][k], row stride 112B
    __shared__ __align__(16) ushort Bs[64][56];   // [n][k]

    const int t  = threadIdx.x;
    const int m0 = blockIdx.x * 64;   // 4
    const int n0 = blockIdx.y * 64;   // 8
    const int z  = blockIdx.z;        // 8
    const int step0 = z * 19;
    const int nstep = min(19, 149 - step0);

    const int r = t >> 2;             // 0..63  (staging row)
    const int c = t & 3;              // 0..3   (staging 8-elem chunk)
    const int l = t & 63;
    const int w = t >> 6;             // wave 0..3
    const int lm = l & 15;
    const int kb = l >> 4;            // 0..3

    f32x4 zero = {0.f, 0.f, 0.f, 0.f};
    f32x4 acc[4] = {zero, zero, zero, zero};

    const ushort* eA = E   + (size_t)(m0 + r) * KPAD + c * 8;
    const ushort* eB = W1T + (size_t)(n0 + r) * KPAD + c * 8;

    int k0 = step0 * 32;
    float4 av = *(const float4*)(eA + k0);
    float4 bv = *(const float4*)(eB + k0);

    for (int s = 0; s < nstep; ++s) {
        *(float4*)&As[r][c * 8] = av;
        *(float4*)&Bs[r][c * 8] = bv;
        __syncthreads();
        if (s + 1 < nstep) {                    // prefetch next tile
            int kn = (step0 + s + 1) * 32;
            av = *(const float4*)(eA + kn);
            bv = *(const float4*)(eB + kn);
        }
        bf16x8 a = *(const bf16x8*)&As[w * 16 + lm][kb * 8];
        #pragma unroll
        for (int j = 0; j < 4; ++j) {
            bf16x8 b = *(const bf16x8*)&Bs[j * 16 + lm][kb * 8];
            acc[j] = __builtin_amdgcn_mfma_f32_16x16x32_bf16(a, b, acc[j], 0, 0, 0);
        }
        __syncthreads();
    }

    // C/D layout: col = lane&15 (n), row = (lane>>4)*4 + reg (m)
    const int mrow = m0 + w * 16 + kb * 4;
    #pragma unroll
    for (int j = 0; j < 4; ++j) {
        int n = n0 + j * 16 + lm;
        #pragma unroll
        for (int rg = 0; rg < 4; ++rg)
            Cpart[((size_t)z * SBN + mrow + rg) * HD + n] = acc[j][rg];
    }
}

// ---------------------------------------------------------------------------
// K3: h = relu(sum(Cpart)*inv_denom + b1); two MLP heads; write mean/std/z
// 128 blocks x 2 images each.
__global__ __launch_bounds__(256) void mlp_kernel(
    const float* __restrict__ Cpart, const float* __restrict__ inv_denom,
    const float* __restrict__ b1,
    const float* __restrict__ Wm1, const float* __restrict__ bm1,
    const float* __restrict__ Wm2, const float* __restrict__ bm2,
    const float* __restrict__ Ws1, const float* __restrict__ bs1,
    const float* __restrict__ Ws2, const float* __restrict__ bs2,
    const float* __restrict__ eps, float* __restrict__ out,
    float* __restrict__ z_cur, int k)
{
    __shared__ float hsh[2][HD];
    __shared__ float hm[2][256];
    __shared__ float hs[2][256];
    __shared__ float res_sh[2][2][2];

    const int t = threadIdx.x;
    const int ib0 = blockIdx.x * 2;

    for (int q = 0; q < 2; ++q) {
        int ib = ib0 + q;
        float idn = inv_denom[ib];
        for (int n = t; n < HD; n += 256) {
            float s = 0.f;
            #pragma unroll
            for (int z = 0; z < SPLITK; ++z)
                s += Cpart[((size_t)z * SBN + ib) * HD + n];
            hsh[q][n] = fmaxf(fmaf(s, idn, b1[n]), 0.f);
        }
    }
    __syncthreads();

    {
        float am[2] = {0.f, 0.f};
        float as_[2] = {0.f, 0.f};
        for (int i = 0; i < HD; ++i) {
            float wm = Wm1[(size_t)i * 256 + t];
            float ws = Ws1[(size_t)i * 256 + t];
            #pragma unroll
            for (int q = 0; q < 2; ++q) {
                am[q]  = fmaf(hsh[q][i], wm, am[q]);
                as_[q] = fmaf(hsh[q][i], ws, as_[q]);
            }
        }
        float bmv = bm1[t], bsv = bs1[t];
        #pragma unroll
        for (int q = 0; q < 2; ++q) {
            hm[q][t] = fmaxf(am[q] + bmv, 0.f);
            hs[q][t] = fmaxf(as_[q] + bsv, 0.f);
        }
    }
    __syncthreads();

    if (t < 8) {
        int q = t >> 2, zd = (t >> 1) & 1, which = t & 1;
        const float* W2 = which ? Ws2 : Wm2;
        const float* h2 = which ? hs[q] : hm[q];
        float acc = 0.f;
        for (int i = 0; i < 256; ++i) acc = fmaf(h2[i], W2[(size_t)i * 2 + zd], acc);
        float res = which ? __expf(acc + bs2[zd]) : tanhf(acc + bm2[zd]);
        res_sh[q][zd][which] = res;
    }
    __syncthreads();
    if (t < 4) {
        int q = t >> 1, zd = t & 1;
        int ib = ib0 + q;
        float mean = res_sh[q][zd][0];
        float stdv = res_sh[q][zd][1];
        float ev = eps[(size_t)ib * (KKC * ZDD) + k * ZDD + zd];
        float z = fmaf(stdv, ev, mean);
        int oidx = ib * (KKC * ZDD) + k * ZDD + zd;
        out[oidx]        = mean;   // q_mean
        out[1536 + oidx] = stdv;   // q_std
        out[3072 + oidx] = z;      // z_where
        z_cur[ib * 2 + zd] = z;
    }
}

// ---------------------------------------------------------------------------
// K4: frame_left -= place_digit(conv_kernel[:,:,k], z)   (bilinear, zero pad)
__global__ __launch_bounds__(256) void recon_kernel(
    float* __restrict__ frameL, const float* __restrict__ conv_kernel,
    const float* __restrict__ z_cur, int k)
{
    __shared__ float dg[DPD * DPD];
    const int t = threadIdx.x, ib = blockIdx.x;
    const float zx = z_cur[ib * 2 + 0];
    const float zy = z_cur[ib * 2 + 1];
    const float* ks = conv_kernel + ((size_t)ib * KKC + k) * (DPD * DPD);
    for (int i = t; i < DPD * DPD; i += 256) dg[i] = ks[i];
    __syncthreads();

    const float scale = (float)FPD / (float)DPD;
    for (int p = t; p < 9216; p += 256) {
        int i = p / 96;
        int j = p - i * 96;
        float oci = (2.f * i + 1.f) / 96.f - 1.f;
        float ocj = (2.f * j + 1.f) / 96.f - 1.f;
        float py = ((scale * (oci - zy) + 1.f) * 28.f - 1.f) * 0.5f;
        float px = ((scale * (ocj - zx) + 1.f) * 28.f - 1.f) * 0.5f;
        float py0f = floorf(py), px0f = floorf(px);
        float fy = py - py0f, fx = px - px0f;
        int y0 = (int)py0f, x0 = (int)px0f;
        int y1 = y0 + 1, x1 = x0 + 1;
        float wy0 = (y0 >= 0 && y0 < DPD) ? 1.f - fy : 0.f;
        float wy1 = (y1 >= 0 && y1 < DPD) ? fy : 0.f;
        float wx0 = (x0 >= 0 && x0 < DPD) ? 1.f - fx : 0.f;
        float wx1 = (x1 >= 0 && x1 < DPD) ? fx : 0.f;
        int y0c = min(max(y0, 0), DPD - 1), y1c = min(max(y1, 0), DPD - 1);
        int x0c = min(max(x0, 0), DPD - 1), x1c = min(max(x1, 0), DPD - 1);
        float tmp0 = wy0 * dg[y0c * DPD + x0c] + wy1 * dg[y1c * DPD + x0c];
        float tmp1 = wy0 * dg[y0c * DPD + x1c] + wy1 * dg[y1c * DPD + x1c];
        float recon = wx0 * tmp0 + wx1 * tmp1;
        frameL[(size_t)ib * 9216 + p] -= recon;
    }
}

// ---------------------------------------------------------------------------
extern "C" void kernel_launch(void* const* d_in, const int* in_sizes, int n_in,
                              void* d_out, int out_size, void* d_ws, size_t ws_size,
                              hipStream_t stream)
{
    const float* frames = (const float*)d_in[0];
    const float* ck     = (const float*)d_in[1];
    const float* eps    = (const float*)d_in[2];
    const float* W1     = (const float*)d_in[3];
    const float* b1     = (const float*)d_in[4];
    const float* Wm1    = (const float*)d_in[5];
    const float* bm1    = (const float*)d_in[6];
    const float* Wm2    = (const float*)d_in[7];
    const float* bm2    = (const float*)d_in[8];
    const float* Ws1    = (const float*)d_in[9];
    const float* bs1    = (const float*)d_in[10];
    const float* Ws2    = (const float*)d_in[11];
    const float* bs2    = (const float*)d_in[12];
    const int*   tsp    = (const int*)d_in[13];
    float* out = (float*)d_out;

    float* frameL  = (float*)d_ws;                  // 2359296 f
    float* Cpart   = frameL + 2359296;              // 1048576 f
    float* inv_den = Cpart + 1048576;               // 256 f
    float* z_cur   = inv_den + 256;                 // 512 f
    ushort* e_buf  = (ushort*)(z_cur + 512);        // 256*KPAD bf16
    ushort* W1T    = e_buf + (size_t)SBN * KPAD;    // 512*KPAD bf16

    init_frame_kernel<<<2304, 256, 0, stream>>>(
        (const float4*)frames, tsp, (float4*)frameL);
    w1t_kernel<<<dim3(75, 8), 256, 0, stream>>>(W1, W1T);

    for (int k = 0; k < KKC; ++k) {
        conv_softmax_kernel<<<256, 1024, 0, stream>>>(frameL, ck, e_buf, inv_den, k);
        gemm1_mfma<<<dim3(4, 8, 8), 256, 0, stream>>>(e_buf, W1T, Cpart);
        mlp_kernel<<<128, 256, 0, stream>>>(Cpart, inv_den, b1,
                                            Wm1, bm1, Wm2, bm2,
                                            Ws1, bs1, Ws2, bs2,
                                            eps, out, z_cur, k);
        if (k < KKC - 1)
            recon_kernel<<<256, 256, 0, stream>>>(frameL, ck, z_cur, k);
    }
}

// Round 3
// 399.470 us; speedup vs baseline: 1.7021x; 1.2325x over previous
//
#include <hip/hip_runtime.h>
#include <hip/hip_bf16.h>
#include <math.h>

// Problem constants
#define FPD 96      // frame size
#define DPD 28      // digit/kernel size
#define CPD 69      // FPD - DPD + 1
#define NPD 4761    // CPD*CPD
#define KKC 3       // K iterations
#define SBN 256     // S*B images
#define TT 8        // T
#define HD 512      // H
#define ZDD 2
#define KPAD 4768   // 149*32, padded K for MFMA GEMM

#define SPLITK 8
#define FRS 100     // frame LDS row stride (mult of 4, mod 32 = 4)

typedef __attribute__((ext_vector_type(8))) short bf16x8;
typedef __attribute__((ext_vector_type(4))) float f32x4;

// ---------------------------------------------------------------------------
// K0b: W1T[n][k] = bf16(W1[k][n]), k padded to KPAD with zeros. Once per launch.
__global__ __launch_bounds__(256) void w1t_kernel(
    const float* __restrict__ W1, ushort* __restrict__ W1T)
{
    __shared__ ushort tile[64][65];
    const int k0 = blockIdx.x * 64;    // 75 blocks covers 4800 >= KPAD
    const int n0 = blockIdx.y * 64;    // 8 blocks
    const int t = threadIdx.x;
    const int ln = t & 63;
    const int lr = t >> 6;             // 0..3

    #pragma unroll
    for (int i = 0; i < 16; ++i) {
        int kk = k0 + lr + i * 4;
        float v = (kk < NPD) ? W1[(size_t)kk * HD + n0 + ln] : 0.f;
        __hip_bfloat16 h = __float2bfloat16(v);
        tile[lr + i * 4][ln] = *reinterpret_cast<ushort*>(&h);
    }
    __syncthreads();
    #pragma unroll
    for (int i = 0; i < 16; ++i) {
        int nn = lr + i * 4;
        int kk = k0 + ln;
        if (kk < KPAD)
            W1T[(size_t)(n0 + nn) * KPAD + kk] = tile[ln][nn];
    }
}

// ---------------------------------------------------------------------------
// K1: depthwise valid conv (96x96 * 28x28 -> 69x69) + softmax-exp (bf16).
// One block (1024 threads) per image. Tasks: 69 oy x 6 tiles(12 wide) x 2
// dy-halves = 828; each half owns a cv slab (no atomics); all LDS window
// reads are aligned ds_read_b128.
__global__ __launch_bounds__(1024) void conv_softmax_kernel(
    const float* __restrict__ frames, const int* __restrict__ tsp,
    const float* __restrict__ frameL, const float* __restrict__ conv_kernel,
    ushort* __restrict__ e_buf, float* __restrict__ inv_denom, int k)
{
    __shared__ __align__(16) float fr[96 * FRS];
    __shared__ __align__(16) float kr[DPD * DPD];
    __shared__ float cv0[NPD];
    __shared__ float cv1[NPD];
    __shared__ float red[32];

    const int t = threadIdx.x;
    const int ib = blockIdx.x;

    const float* src = (k == 0)
        ? frames + ((size_t)ib * TT + *tsp) * 9216
        : frameL + (size_t)ib * 9216;
    for (int i = t; i < 9216; i += 1024) {
        int r = i / 96, c = i - r * 96;
        fr[r * FRS + c] = src[i];
    }
    for (int i = t; i < 96 * 4; i += 1024)       // zero pad cols 96..99
        fr[(i >> 2) * FRS + 96 + (i & 3)] = 0.f;
    const float* ks = conv_kernel + ((size_t)ib * KKC + k) * 784;
    if (t < 784) kr[t] = ks[t];
    __syncthreads();

    if (t < 828) {
        const int half = (t >= 414) ? 1 : 0;
        const int rem  = t - half * 414;
        const int oy   = rem / 6;
        const int ox0  = (rem - oy * 6) * 12;

        float acc[12] = {0.f,0.f,0.f,0.f,0.f,0.f,0.f,0.f,0.f,0.f,0.f,0.f};
        const int dy0 = half * 14;
        for (int d = 0; d < 14; ++d) {
            const int dy = dy0 + d;
            const float* frow = &fr[(oy + dy) * FRS + ox0];
            const float* krow = &kr[dy * 28];
            float4 c0 = *(const float4*)(frow);
            float4 c1 = *(const float4*)(frow + 4);
            float4 c2 = *(const float4*)(frow + 8);
            float4 c3 = *(const float4*)(frow + 12);
            #pragma unroll
            for (int dx = 0; dx < 28; dx += 4) {
                float4 kv = *(const float4*)(krow + dx);
                float w[16] = {c0.x,c0.y,c0.z,c0.w, c1.x,c1.y,c1.z,c1.w,
                               c2.x,c2.y,c2.z,c2.w, c3.x,c3.y,c3.z,c3.w};
                float kk4[4] = {kv.x, kv.y, kv.z, kv.w};
                #pragma unroll
                for (int i = 0; i < 4; ++i)
                    #pragma unroll
                    for (int j = 0; j < 12; ++j)
                        acc[j] = fmaf(w[i + j], kk4[i], acc[j]);
                c0 = c1; c1 = c2; c2 = c3;
                if (dx < 24) c3 = *(const float4*)(frow + dx + 16);
            }
        }
        float* cvh = half ? cv1 : cv0;
        const int base = oy * CPD + ox0;
        #pragma unroll
        for (int j = 0; j < 12; ++j)
            if (ox0 + j < CPD) cvh[base + j] = acc[j];
    }
    __syncthreads();

    // merge halves + block max (16 waves)
    float m = -INFINITY;
    for (int i = t; i < NPD; i += 1024) {
        float v = cv0[i] + cv1[i];
        cv0[i] = v;
        m = fmaxf(m, v);
    }
    #pragma unroll
    for (int off = 32; off > 0; off >>= 1) m = fmaxf(m, __shfl_down(m, off, 64));
    int lane = t & 63, wid = t >> 6;
    if (lane == 0) red[wid] = m;
    __syncthreads();
    m = red[0];
    #pragma unroll
    for (int i = 1; i < 16; ++i) m = fmaxf(m, red[i]);

    // exp (bf16 out) + sum
    float s = 0.f;
    ushort* eo = e_buf + (size_t)ib * KPAD;
    for (int i = t; i < NPD; i += 1024) {
        float ev = __expf(cv0[i] - m);
        __hip_bfloat16 h = __float2bfloat16(ev);
        eo[i] = *reinterpret_cast<ushort*>(&h);
        s += ev;
    }
    #pragma unroll
    for (int off = 32; off > 0; off >>= 1) s += __shfl_down(s, off, 64);
    if (lane == 0) red[16 + wid] = s;
    __syncthreads();
    if (t == 0) {
        float tot = 0.f;
        #pragma unroll
        for (int i = 0; i < 16; ++i) tot += red[16 + i];
        inv_denom[ib] = 1.0f / tot;
    }
    if (t < KPAD - NPD) eo[NPD + t] = 0;   // zero k-padding
}

// ---------------------------------------------------------------------------
// K2: Cpart[z] = E(256xKPAD bf16) @ W1T^T (KPADx512 bf16), split-K=8, MFMA
__global__ __launch_bounds__(256) void gemm1_mfma(
    const ushort* __restrict__ E, const ushort* __restrict__ W1T,
    float* __restrict__ Cpart)
{
    __shared__ __align__(16) ushort As[64][56];   // [m][k], row stride 112B
    __shared__ __align__(16) ushort Bs[64][56];   // [n][k]

    const int t  = threadIdx.x;
    const int m0 = blockIdx.x * 64;   // 4
    const int n0 = blockIdx.y * 64;   // 8
    const int z  = blockIdx.z;        // 8
    const int step0 = z * 19;
    const int nstep = min(19, 149 - step0);

    const int r = t >> 2;             // 0..63  (staging row)
    const int c = t & 3;              // 0..3   (staging 8-elem chunk)
    const int l = t & 63;
    const int w = t >> 6;             // wave 0..3
    const int lm = l & 15;
    const int kb = l >> 4;            // 0..3

    f32x4 zero = {0.f, 0.f, 0.f, 0.f};
    f32x4 acc[4] = {zero, zero, zero, zero};

    const ushort* eA = E   + (size_t)(m0 + r) * KPAD + c * 8;
    const ushort* eB = W1T + (size_t)(n0 + r) * KPAD + c * 8;

    int k0 = step0 * 32;
    float4 av = *(const float4*)(eA + k0);
    float4 bv = *(const float4*)(eB + k0);

    for (int s = 0; s < nstep; ++s) {
        *(float4*)&As[r][c * 8] = av;
        *(float4*)&Bs[r][c * 8] = bv;
        __syncthreads();
        if (s + 1 < nstep) {                    // prefetch next tile
            int kn = (step0 + s + 1) * 32;
            av = *(const float4*)(eA + kn);
            bv = *(const float4*)(eB + kn);
        }
        bf16x8 a = *(const bf16x8*)&As[w * 16 + lm][kb * 8];
        #pragma unroll
        for (int j = 0; j < 4; ++j) {
            bf16x8 b = *(const bf16x8*)&Bs[j * 16 + lm][kb * 8];
            acc[j] = __builtin_amdgcn_mfma_f32_16x16x32_bf16(a, b, acc[j], 0, 0, 0);
        }
        __syncthreads();
    }

    // C/D layout: col = lane&15 (n), row = (lane>>4)*4 + reg (m)
    const int mrow = m0 + w * 16 + kb * 4;
    #pragma unroll
    for (int j = 0; j < 4; ++j) {
        int n = n0 + j * 16 + lm;
        #pragma unroll
        for (int rg = 0; rg < 4; ++rg)
            Cpart[((size_t)z * SBN + mrow + rg) * HD + n] = acc[j][rg];
    }
}

// ---------------------------------------------------------------------------
// K3: h = relu(sum(Cpart)*inv_denom + b1); two MLP heads; write mean/std/z
__global__ __launch_bounds__(256) void mlp_kernel(
    const float* __restrict__ Cpart, const float* __restrict__ inv_denom,
    const float* __restrict__ b1,
    const float* __restrict__ Wm1, const float* __restrict__ bm1,
    const float* __restrict__ Wm2, const float* __restrict__ bm2,
    const float* __restrict__ Ws1, const float* __restrict__ bs1,
    const float* __restrict__ Ws2, const float* __restrict__ bs2,
    const float* __restrict__ eps, float* __restrict__ out,
    float* __restrict__ z_cur, int k)
{
    __shared__ float hsh[2][HD];
    __shared__ float hm[2][256];
    __shared__ float hs[2][256];
    __shared__ float res_sh[2][2][2];

    const int t = threadIdx.x;
    const int ib0 = blockIdx.x * 2;

    for (int q = 0; q < 2; ++q) {
        int ib = ib0 + q;
        float idn = inv_denom[ib];
        for (int n = t; n < HD; n += 256) {
            float s = 0.f;
            #pragma unroll
            for (int z = 0; z < SPLITK; ++z)
                s += Cpart[((size_t)z * SBN + ib) * HD + n];
            hsh[q][n] = fmaxf(fmaf(s, idn, b1[n]), 0.f);
        }
    }
    __syncthreads();

    {
        float am[2] = {0.f, 0.f};
        float as_[2] = {0.f, 0.f};
        for (int i = 0; i < HD; ++i) {
            float wm = Wm1[(size_t)i * 256 + t];
            float ws = Ws1[(size_t)i * 256 + t];
            #pragma unroll
            for (int q = 0; q < 2; ++q) {
                am[q]  = fmaf(hsh[q][i], wm, am[q]);
                as_[q] = fmaf(hsh[q][i], ws, as_[q]);
            }
        }
        float bmv = bm1[t], bsv = bs1[t];
        #pragma unroll
        for (int q = 0; q < 2; ++q) {
            hm[q][t] = fmaxf(am[q] + bmv, 0.f);
            hs[q][t] = fmaxf(as_[q] + bsv, 0.f);
        }
    }
    __syncthreads();

    if (t < 8) {
        int q = t >> 2, zd = (t >> 1) & 1, which = t & 1;
        const float* W2 = which ? Ws2 : Wm2;
        const float* h2 = which ? hs[q] : hm[q];
        float acc = 0.f;
        for (int i = 0; i < 256; ++i) acc = fmaf(h2[i], W2[(size_t)i * 2 + zd], acc);
        float res = which ? __expf(acc + bs2[zd]) : tanhf(acc + bm2[zd]);
        res_sh[q][zd][which] = res;
    }
    __syncthreads();
    if (t < 4) {
        int q = t >> 1, zd = t & 1;
        int ib = ib0 + q;
        float mean = res_sh[q][zd][0];
        float stdv = res_sh[q][zd][1];
        float ev = eps[(size_t)ib * (KKC * ZDD) + k * ZDD + zd];
        float z = fmaf(stdv, ev, mean);
        int oidx = ib * (KKC * ZDD) + k * ZDD + zd;
        out[oidx]        = mean;   // q_mean
        out[1536 + oidx] = stdv;   // q_std
        out[3072 + oidx] = z;      // z_where
        z_cur[ib * 2 + zd] = z;
    }
}

// ---------------------------------------------------------------------------
// K4: frame_left = prev - place_digit(conv_kernel[:,:,k], z)
// prev = frames[:,timestep] for k==0 (init fused), else frameL.
__global__ __launch_bounds__(256) void recon_kernel(
    const float* __restrict__ frames, const int* __restrict__ tsp,
    float* __restrict__ frameL, const float* __restrict__ conv_kernel,
    const float* __restrict__ z_cur, int k)
{
    __shared__ float dg[DPD * DPD];
    const int t = threadIdx.x, ib = blockIdx.x;
    const float zx = z_cur[ib * 2 + 0];
    const float zy = z_cur[ib * 2 + 1];
    const float* ks = conv_kernel + ((size_t)ib * KKC + k) * (DPD * DPD);
    for (int i = t; i < DPD * DPD; i += 256) dg[i] = ks[i];
    __syncthreads();

    const float* prev = (k == 0)
        ? frames + ((size_t)ib * TT + *tsp) * 9216
        : frameL + (size_t)ib * 9216;

    const float scale = (float)FPD / (float)DPD;
    for (int p = t; p < 9216; p += 256) {
        int i = p / 96;
        int j = p - i * 96;
        float oci = (2.f * i + 1.f) / 96.f - 1.f;
        float ocj = (2.f * j + 1.f) / 96.f - 1.f;
        float py = ((scale * (oci - zy) + 1.f) * 28.f - 1.f) * 0.5f;
        float px = ((scale * (ocj - zx) + 1.f) * 28.f - 1.f) * 0.5f;
        float py0f = floorf(py), px0f = floorf(px);
        float fy = py - py0f, fx = px - px0f;
        int y0 = (int)py0f, x0 = (int)px0f;
        int y1 = y0 + 1, x1 = x0 + 1;
        float wy0 = (y0 >= 0 && y0 < DPD) ? 1.f - fy : 0.f;
        float wy1 = (y1 >= 0 && y1 < DPD) ? fy : 0.f;
        float wx0 = (x0 >= 0 && x0 < DPD) ? 1.f - fx : 0.f;
        float wx1 = (x1 >= 0 && x1 < DPD) ? fx : 0.f;
        int y0c = min(max(y0, 0), DPD - 1), y1c = min(max(y1, 0), DPD - 1);
        int x0c = min(max(x0, 0), DPD - 1), x1c = min(max(x1, 0), DPD - 1);
        float tmp0 = wy0 * dg[y0c * DPD + x0c] + wy1 * dg[y1c * DPD + x0c];
        float tmp1 = wy0 * dg[y0c * DPD + x1c] + wy1 * dg[y1c * DPD + x1c];
        float recon = wx0 * tmp0 + wx1 * tmp1;
        frameL[(size_t)ib * 9216 + p] = prev[p] - recon;
    }
}

// ---------------------------------------------------------------------------
extern "C" void kernel_launch(void* const* d_in, const int* in_sizes, int n_in,
                              void* d_out, int out_size, void* d_ws, size_t ws_size,
                              hipStream_t stream)
{
    const float* frames = (const float*)d_in[0];
    const float* ck     = (const float*)d_in[1];
    const float* eps    = (const float*)d_in[2];
    const float* W1     = (const float*)d_in[3];
    const float* b1     = (const float*)d_in[4];
    const float* Wm1    = (const float*)d_in[5];
    const float* bm1    = (const float*)d_in[6];
    const float* Wm2    = (const float*)d_in[7];
    const float* bm2    = (const float*)d_in[8];
    const float* Ws1    = (const float*)d_in[9];
    const float* bs1    = (const float*)d_in[10];
    const float* Ws2    = (const float*)d_in[11];
    const float* bs2    = (const float*)d_in[12];
    const int*   tsp    = (const int*)d_in[13];
    float* out = (float*)d_out;

    float* frameL  = (float*)d_ws;                  // 2359296 f
    float* Cpart   = frameL + 2359296;              // 1048576 f
    float* inv_den = Cpart + 1048576;               // 256 f
    float* z_cur   = inv_den + 256;                 // 512 f
    ushort* e_buf  = (ushort*)(z_cur + 512);        // 256*KPAD bf16
    ushort* W1T    = e_buf + (size_t)SBN * KPAD;    // 512*KPAD bf16

    w1t_kernel<<<dim3(75, 8), 256, 0, stream>>>(W1, W1T);

    for (int k = 0; k < KKC; ++k) {
        conv_softmax_kernel<<<256, 1024, 0, stream>>>(
            frames, tsp, frameL, ck, e_buf, inv_den, k);
        gemm1_mfma<<<dim3(4, 8, 8), 256, 0, stream>>>(e_buf, W1T, Cpart);
        mlp_kernel<<<128, 256, 0, stream>>>(Cpart, inv_den, b1,
                                            Wm1, bm1, Wm2, bm2,
                                            Ws1, bs1, Ws2, bs2,
                                            eps, out, z_cur, k);
        if (k < KKC - 1)
            recon_kernel<<<256, 256, 0, stream>>>(frames, tsp, frameL, ck, z_cur, k);
    }
}

// Round 4
// 345.651 us; speedup vs baseline: 1.9671x; 1.1557x over previous
//
#include <hip/hip_runtime.h>
#include <hip/hip_bf16.h>
#include <math.h>

// Problem constants
#define FPD 96      // frame size
#define DPD 28      // digit/kernel size
#define CPD 69      // FPD - DPD + 1
#define NPD 4761    // CPD*CPD
#define KKC 3       // K iterations
#define SBN 256     // S*B images
#define TT 8        // T
#define HD 512      // H
#define ZDD 2
#define KPAD 4768   // 149*32, padded K for MFMA GEMM
#define SPLITK 15
#define FRS 100     // frame LDS row stride

typedef __attribute__((ext_vector_type(8))) short bf16x8;
typedef __attribute__((ext_vector_type(4))) float f32x4;

__device__ __forceinline__ float bf2f(ushort u) {
    union { unsigned int i; float f; } v; v.i = ((unsigned int)u) << 16; return v.f;
}

// ---------------------------------------------------------------------------
// W1T[n][k] = bf16(W1[k][n]), k padded to KPAD with zeros. Once per launch.
__global__ __launch_bounds__(256) void w1t_kernel(
    const float* __restrict__ W1, ushort* __restrict__ W1T)
{
    __shared__ ushort tile[64][65];
    const int k0 = blockIdx.x * 64;    // 75 blocks covers 4800 >= KPAD
    const int n0 = blockIdx.y * 64;    // 8 blocks
    const int t = threadIdx.x;
    const int ln = t & 63;
    const int lr = t >> 6;             // 0..3

    #pragma unroll
    for (int i = 0; i < 16; ++i) {
        int kk = k0 + lr + i * 4;
        float v = (kk < NPD) ? W1[(size_t)kk * HD + n0 + ln] : 0.f;
        __hip_bfloat16 h = __float2bfloat16(v);
        tile[lr + i * 4][ln] = *reinterpret_cast<ushort*>(&h);
    }
    __syncthreads();
    #pragma unroll
    for (int i = 0; i < 16; ++i) {
        int nn = lr + i * 4;
        int kk = k0 + ln;
        if (kk < KPAD)
            W1T[(size_t)(n0 + nn) * KPAD + kk] = tile[ln][nn];
    }
}

// ---------------------------------------------------------------------------
// Whid = bf16 concat of Wm1 (head 0) and Ws1 (head 1), each 512x256 row-major.
__global__ __launch_bounds__(256) void whid_kernel(
    const float* __restrict__ Wm1, const float* __restrict__ Ws1,
    ushort* __restrict__ Whid)
{
    int i = blockIdx.x * 256 + threadIdx.x;     // 262144 total
    const float* src = (i >= 131072) ? Ws1 : Wm1;
    float v = src[i & 131071];
    __hip_bfloat16 h = __float2bfloat16(v);
    Whid[i] = *reinterpret_cast<ushort*>(&h);
}

// ---------------------------------------------------------------------------
// Conv + fused recon-subtract + softmax-exp (bf16 out).
// One block (1024 threads) per image. Tasks: 69 oy x 3 tiles(24 wide) x 4
// dy-quarters = 828; each quarter owns a cv slab; window reads are b128,
// kernel-row reads are wave-broadcast.
// k==0: src=frames, no recon.  k==1: src=frames, subtract recon(z0), write
// frameL.  k==2: src=frameL, subtract recon(z1).
__global__ __launch_bounds__(1024) void conv_softmax_kernel(
    const float* __restrict__ frames, const int* __restrict__ tsp,
    float* __restrict__ frameL, const float* __restrict__ ck,
    const float* __restrict__ z_cur,
    ushort* __restrict__ e_buf, float* __restrict__ inv_denom, int k)
{
    __shared__ __align__(16) float fr[96 * FRS];
    __shared__ __align__(16) float kr[784];
    __shared__ float dg[784];
    __shared__ float cv[4][NPD];
    __shared__ float red[32];

    const int t = threadIdx.x;
    const int ib = blockIdx.x;

    if (t < 784) {
        kr[t] = ck[((size_t)ib * KKC + k) * 784 + t];
        if (k > 0) dg[t] = ck[((size_t)ib * KKC + (k - 1)) * 784 + t];
    }
    float zx = 0.f, zy = 0.f;
    if (k > 0) { zx = z_cur[ib * 2]; zy = z_cur[ib * 2 + 1]; }
    __syncthreads();

    const float* src = (k < 2)
        ? frames + ((size_t)ib * TT + *tsp) * 9216
        : frameL + (size_t)ib * 9216;
    const float scale = 96.f / 28.f;
    for (int p = t; p < 9216; p += 1024) {
        int r = p / 96, c = p - r * 96;
        float val = src[p];
        if (k > 0) {
            float oci = (2.f * r + 1.f) / 96.f - 1.f;
            float ocj = (2.f * c + 1.f) / 96.f - 1.f;
            float py = ((scale * (oci - zy) + 1.f) * 28.f - 1.f) * 0.5f;
            float px = ((scale * (ocj - zx) + 1.f) * 28.f - 1.f) * 0.5f;
            float py0f = floorf(py), px0f = floorf(px);
            float fy = py - py0f, fx = px - px0f;
            int y0 = (int)py0f, x0 = (int)px0f;
            int y1 = y0 + 1, x1 = x0 + 1;
            float wy0 = (y0 >= 0 && y0 < DPD) ? 1.f - fy : 0.f;
            float wy1 = (y1 >= 0 && y1 < DPD) ? fy : 0.f;
            float wx0 = (x0 >= 0 && x0 < DPD) ? 1.f - fx : 0.f;
            float wx1 = (x1 >= 0 && x1 < DPD) ? fx : 0.f;
            int y0c = min(max(y0, 0), DPD - 1), y1c = min(max(y1, 0), DPD - 1);
            int x0c = min(max(x0, 0), DPD - 1), x1c = min(max(x1, 0), DPD - 1);
            float tmp0 = wy0 * dg[y0c * DPD + x0c] + wy1 * dg[y1c * DPD + x0c];
            float tmp1 = wy0 * dg[y0c * DPD + x1c] + wy1 * dg[y1c * DPD + x1c];
            val -= wx0 * tmp0 + wx1 * tmp1;
        }
        fr[r * FRS + c] = val;
        if (k == 1) frameL[(size_t)ib * 9216 + p] = val;
    }
    if (t < 384) fr[(t >> 2) * FRS + 96 + (t & 3)] = 0.f;  // zero pad cols 96..99
    __syncthreads();

    if (t < 828) {
        const int q    = t / 207;
        const int rem  = t - q * 207;
        const int oy   = rem / 3;
        const int tile = rem - oy * 3;
        const int ox0  = tile * 24;
        const int dy0  = q * 7;

        float acc[24];
        #pragma unroll
        for (int j = 0; j < 24; ++j) acc[j] = 0.f;

        for (int dd = 0; dd < 7; ++dd) {
            const int dy = dy0 + dd;
            const float* frow = &fr[(oy + dy) * FRS + ox0];
            const float* krow = &kr[dy * 28];
            float w[28];
            #pragma unroll
            for (int u = 0; u < 7; ++u) {
                float4 v = *(const float4*)(frow + 4 * u);
                w[4*u] = v.x; w[4*u+1] = v.y; w[4*u+2] = v.z; w[4*u+3] = v.w;
            }
            #pragma unroll
            for (int d = 0; d < 28; d += 4) {
                float4 kv = *(const float4*)(krow + d);
                float kk4[4] = {kv.x, kv.y, kv.z, kv.w};
                #pragma unroll
                for (int i = 0; i < 4; ++i)
                    #pragma unroll
                    for (int j = 0; j < 24; ++j)
                        acc[j] = fmaf(w[i + j], kk4[i], acc[j]);
                if (d < 24) {
                    #pragma unroll
                    for (int qq = 0; qq < 24; ++qq) w[qq] = w[qq + 4];
                    float4 nv = *(const float4*)(frow + d + 28);
                    w[24] = nv.x; w[25] = nv.y; w[26] = nv.z; w[27] = nv.w;
                }
            }
        }
        float* cvq = &cv[q][oy * CPD + ox0];
        #pragma unroll
        for (int j = 0; j < 24; ++j)
            if (ox0 + j < CPD) cvq[j] = acc[j];
    }
    __syncthreads();

    // merge quarters + block max (16 waves)
    float m = -INFINITY;
    for (int i = t; i < NPD; i += 1024) {
        float v = cv[0][i] + cv[1][i] + cv[2][i] + cv[3][i];
        cv[0][i] = v;
        m = fmaxf(m, v);
    }
    #pragma unroll
    for (int off = 32; off > 0; off >>= 1) m = fmaxf(m, __shfl_down(m, off, 64));
    int lane = t & 63, wid = t >> 6;
    if (lane == 0) red[wid] = m;
    __syncthreads();
    m = red[0];
    #pragma unroll
    for (int i = 1; i < 16; ++i) m = fmaxf(m, red[i]);

    float s = 0.f;
    ushort* eo = e_buf + (size_t)ib * KPAD;
    for (int i = t; i < NPD; i += 1024) {
        float ev = __expf(cv[0][i] - m);
        __hip_bfloat16 h = __float2bfloat16(ev);
        eo[i] = *reinterpret_cast<ushort*>(&h);
        s += ev;
    }
    #pragma unroll
    for (int off = 32; off > 0; off >>= 1) s += __shfl_down(s, off, 64);
    if (lane == 0) red[16 + wid] = s;
    __syncthreads();
    if (t == 0) {
        float tot = 0.f;
        #pragma unroll
        for (int i = 0; i < 16; ++i) tot += red[16 + i];
        inv_denom[ib] = 1.0f / tot;
    }
    if (t < KPAD - NPD) eo[NPD + t] = 0;   // zero k-padding
}

// ---------------------------------------------------------------------------
// h_acc += E(256xKPAD bf16) @ W1T^T (KPADx512 bf16), split-K=15, MFMA,
// atomicAdd epilogue (h_acc pre-zeroed).
__global__ __launch_bounds__(256) void gemm1_mfma(
    const ushort* __restrict__ E, const ushort* __restrict__ W1T,
    float* __restrict__ h_acc)
{
    __shared__ __align__(16) ushort As[64][56];   // [m][k]
    __shared__ __align__(16) ushort Bs[64][56];   // [n][k]

    const int t  = threadIdx.x;
    const int m0 = blockIdx.x * 64;   // 4
    const int n0 = blockIdx.y * 64;   // 8
    const int z  = blockIdx.z;        // 15
    const int step0 = z * 10;
    const int nstep = min(10, 149 - step0);   // z=14 -> 9

    const int r = t >> 2;             // 0..63
    const int c = t & 3;              // 0..3
    const int l = t & 63;
    const int w = t >> 6;             // wave 0..3
    const int lm = l & 15;
    const int kb = l >> 4;            // 0..3

    f32x4 zero = {0.f, 0.f, 0.f, 0.f};
    f32x4 acc[4] = {zero, zero, zero, zero};

    const ushort* eA = E   + (size_t)(m0 + r) * KPAD + c * 8;
    const ushort* eB = W1T + (size_t)(n0 + r) * KPAD + c * 8;

    int k0 = step0 * 32;
    float4 av = *(const float4*)(eA + k0);
    float4 bv = *(const float4*)(eB + k0);

    for (int s = 0; s < nstep; ++s) {
        *(float4*)&As[r][c * 8] = av;
        *(float4*)&Bs[r][c * 8] = bv;
        __syncthreads();
        if (s + 1 < nstep) {
            int kn = (step0 + s + 1) * 32;
            av = *(const float4*)(eA + kn);
            bv = *(const float4*)(eB + kn);
        }
        bf16x8 a = *(const bf16x8*)&As[w * 16 + lm][kb * 8];
        #pragma unroll
        for (int j = 0; j < 4; ++j) {
            bf16x8 b = *(const bf16x8*)&Bs[j * 16 + lm][kb * 8];
            acc[j] = __builtin_amdgcn_mfma_f32_16x16x32_bf16(a, b, acc[j], 0, 0, 0);
        }
        __syncthreads();
    }

    // C/D layout: col = lane&15 (n), row = (lane>>4)*4 + reg (m)
    const int mrow = m0 + w * 16 + kb * 4;
    #pragma unroll
    for (int j = 0; j < 4; ++j) {
        int n = n0 + j * 16 + lm;
        #pragma unroll
        for (int rg = 0; rg < 4; ++rg)
            atomicAdd(&h_acc[(size_t)(mrow + rg) * HD + n], acc[j][rg]);
    }
}

// ---------------------------------------------------------------------------
// Fused MLP: h = relu(h_acc*inv_den + b1); hidden (bf16 weights); heads.
// 128 blocks x 512 threads, 2 images per block.
__global__ __launch_bounds__(512) void mlp_fused(
    const float* __restrict__ h_acc, const float* __restrict__ inv_denom,
    const float* __restrict__ b1, const ushort* __restrict__ Whid,
    const float* __restrict__ bm1, const float* __restrict__ bs1,
    const float* __restrict__ Wm2, const float* __restrict__ bm2,
    const float* __restrict__ Ws2, const float* __restrict__ bs2,
    const float* __restrict__ eps, float* __restrict__ out,
    float* __restrict__ z_cur, int k)
{
    __shared__ float hsh[2][HD];
    __shared__ float h2[2][2][256];    // [head][img][col]
    __shared__ float res_sh[2][2][2];  // [img][zd][head]

    const int t = threadIdx.x;
    const int ib0 = blockIdx.x * 2;

    #pragma unroll
    for (int q = 0; q < 2; ++q) {
        int ib = ib0 + q;
        hsh[q][t] = fmaxf(fmaf(h_acc[(size_t)ib * HD + t], inv_denom[ib], b1[t]), 0.f);
    }
    __syncthreads();

    {
        int head = t >> 8, col = t & 255;
        const ushort* W = Whid + (size_t)head * 131072 + col;
        float bias = head ? bs1[col] : bm1[col];
        float a0 = 0.f, a1 = 0.f;
        #pragma unroll 8
        for (int i = 0; i < HD; ++i) {
            float wf = bf2f(W[(size_t)i * 256]);
            a0 = fmaf(hsh[0][i], wf, a0);
            a1 = fmaf(hsh[1][i], wf, a1);
        }
        h2[head][0][col] = fmaxf(a0 + bias, 0.f);
        h2[head][1][col] = fmaxf(a1 + bias, 0.f);
    }
    __syncthreads();

    {
        int w = t >> 6, l = t & 63;
        int img = w >> 2, zd = (w >> 1) & 1, head = w & 1;
        const float* W2 = head ? Ws2 : Wm2;
        float a = 0.f;
        #pragma unroll
        for (int u = 0; u < 4; ++u) {
            int i = l + u * 64;
            a = fmaf(h2[head][img][i], W2[i * 2 + zd], a);
        }
        #pragma unroll
        for (int off = 32; off > 0; off >>= 1) a += __shfl_down(a, off, 64);
        if (l == 0) {
            float r = head ? __expf(a + bs2[zd]) : tanhf(a + bm2[zd]);
            res_sh[img][zd][head] = r;
        }
    }
    __syncthreads();
    if (t < 4) {
        int img = t >> 1, zd = t & 1, ib = ib0 + img;
        float mean = res_sh[img][zd][0];
        float stdv = res_sh[img][zd][1];
        float ev = eps[(size_t)ib * 6 + k * 2 + zd];
        float z = fmaf(stdv, ev, mean);
        int oidx = ib * 6 + k * 2 + zd;
        out[oidx]        = mean;   // q_mean
        out[1536 + oidx] = stdv;   // q_std
        out[3072 + oidx] = z;      // z_where
        z_cur[ib * 2 + zd] = z;
    }
}

// ---------------------------------------------------------------------------
extern "C" void kernel_launch(void* const* d_in, const int* in_sizes, int n_in,
                              void* d_out, int out_size, void* d_ws, size_t ws_size,
                              hipStream_t stream)
{
    const float* frames = (const float*)d_in[0];
    const float* ck     = (const float*)d_in[1];
    const float* eps    = (const float*)d_in[2];
    const float* W1     = (const float*)d_in[3];
    const float* b1     = (const float*)d_in[4];
    const float* Wm1    = (const float*)d_in[5];
    const float* bm1    = (const float*)d_in[6];
    const float* Wm2    = (const float*)d_in[7];
    const float* bm2    = (const float*)d_in[8];
    const float* Ws1    = (const float*)d_in[9];
    const float* bs1    = (const float*)d_in[10];
    const float* Ws2    = (const float*)d_in[11];
    const float* bs2    = (const float*)d_in[12];
    const int*   tsp    = (const int*)d_in[13];
    float* out = (float*)d_out;

    float* frameL  = (float*)d_ws;                  // 2359296 f
    float* h_acc   = frameL + 2359296;              // 131072 f
    float* inv_den = h_acc + 131072;                // 256 f
    float* z_cur   = inv_den + 256;                 // 512 f
    ushort* e_buf  = (ushort*)(z_cur + 512);        // 256*KPAD
    ushort* W1T    = e_buf + (size_t)SBN * KPAD;    // 512*KPAD
    ushort* Whid   = W1T + (size_t)HD * KPAD;       // 262144

    w1t_kernel<<<dim3(75, 8), 256, 0, stream>>>(W1, W1T);
    whid_kernel<<<1024, 256, 0, stream>>>(Wm1, Ws1, Whid);

    for (int k = 0; k < KKC; ++k) {
        hipMemsetAsync(h_acc, 0, (size_t)SBN * HD * sizeof(float), stream);
        conv_softmax_kernel<<<256, 1024, 0, stream>>>(
            frames, tsp, frameL, ck, z_cur, e_buf, inv_den, k);
        gemm1_mfma<<<dim3(4, 8, SPLITK), 256, 0, stream>>>(e_buf, W1T, h_acc);
        mlp_fused<<<128, 512, 0, stream>>>(h_acc, inv_den, b1, Whid,
                                           bm1, bs1, Wm2, bm2, Ws2, bs2,
                                           eps, out, z_cur, k);
    }
}

// Round 5
// 315.598 us; speedup vs baseline: 2.1544x; 1.0952x over previous
//
#include <hip/hip_runtime.h>
#include <hip/hip_bf16.h>
#include <math.h>

// Problem constants
#define FPD 96      // frame size
#define DPD 28      // digit/kernel size
#define CPD 69      // FPD - DPD + 1
#define NPD 4761    // CPD*CPD
#define KKC 3       // K iterations
#define SBN 256     // S*B images
#define TT 8        // T
#define HD 512      // H
#define ZDD 2
#define KPAD 4768   // 149*32, padded K for MFMA GEMM
#define SPLITK 15
#define FRS 100     // frame LDS row stride
#define CVS 72      // cv slab row stride (b128-aligned output writes)

typedef __attribute__((ext_vector_type(8))) short bf16x8;
typedef __attribute__((ext_vector_type(4))) float f32x4;

__device__ __forceinline__ float bf2f_lo(unsigned int u) {
    union { unsigned int i; float f; } v; v.i = u << 16; return v.f;
}
__device__ __forceinline__ float bf2f_hi(unsigned int u) {
    union { unsigned int i; float f; } v; v.i = u & 0xffff0000u; return v.f;
}
__device__ __forceinline__ float bf2f(ushort u) {
    union { unsigned int i; float f; } v; v.i = ((unsigned int)u) << 16; return v.f;
}

// ---------------------------------------------------------------------------
// W1T[n][k] = bf16(W1[k][n]), k padded to KPAD with zeros. Once per launch.
__global__ __launch_bounds__(256) void w1t_kernel(
    const float* __restrict__ W1, ushort* __restrict__ W1T)
{
    __shared__ ushort tile[64][65];
    const int k0 = blockIdx.x * 64;    // 75 blocks covers 4800 >= KPAD
    const int n0 = blockIdx.y * 64;    // 8 blocks
    const int t = threadIdx.x;
    const int ln = t & 63;
    const int lr = t >> 6;             // 0..3

    #pragma unroll
    for (int i = 0; i < 16; ++i) {
        int kk = k0 + lr + i * 4;
        float v = (kk < NPD) ? W1[(size_t)kk * HD + n0 + ln] : 0.f;
        __hip_bfloat16 h = __float2bfloat16(v);
        tile[lr + i * 4][ln] = *reinterpret_cast<ushort*>(&h);
    }
    __syncthreads();
    #pragma unroll
    for (int i = 0; i < 16; ++i) {
        int nn = lr + i * 4;
        int kk = k0 + ln;
        if (kk < KPAD)
            W1T[(size_t)(n0 + nn) * KPAD + kk] = tile[ln][nn];
    }
}

// ---------------------------------------------------------------------------
// WhidT[r][i] = bf16(W_head[i][col]) with r = head*256+col; i contiguous.
__global__ __launch_bounds__(256) void whidt_kernel(
    const float* __restrict__ Wm1, const float* __restrict__ Ws1,
    ushort* __restrict__ WhidT)
{
    __shared__ ushort tile[64][65];
    const int i0 = blockIdx.x * 64;    // 8  (i = source row, 0..511)
    const int r0 = blockIdx.y * 64;    // 8  (r = head*256+col)
    const int t = threadIdx.x;
    const int ln = t & 63;
    const int lr = t >> 6;

    #pragma unroll
    for (int rep = 0; rep < 16; ++rep) {
        int i = i0 + lr + rep * 4;
        int r = r0 + ln;
        const float* src = (r >= 256) ? Ws1 : Wm1;
        float v = src[(size_t)i * 256 + (r & 255)];
        __hip_bfloat16 h = __float2bfloat16(v);
        tile[lr + rep * 4][ln] = *reinterpret_cast<ushort*>(&h);
    }
    __syncthreads();
    #pragma unroll
    for (int rep = 0; rep < 16; ++rep) {
        int r = r0 + lr + rep * 4;
        WhidT[(size_t)r * 512 + i0 + ln] = tile[ln][lr + rep * 4];
    }
}

// ---------------------------------------------------------------------------
// Conv + fused recon-subtract + softmax-exp (bf16 out).
// One block (1024 threads) per image. Tasks: 69 oy x 3 tiles(24 wide) x 4
// dy-quarters = 828. Window loaded as 13 ds_read_b128 per dy, 672 FMAs with
// static indices (no register shifting). cv slabs stride-72 for b128 stores.
__global__ __launch_bounds__(1024) void conv_softmax_kernel(
    const float* __restrict__ frames, const int* __restrict__ tsp,
    float* __restrict__ frameL, const float* __restrict__ ck,
    const float* __restrict__ z_cur,
    ushort* __restrict__ e_buf, float* __restrict__ inv_denom, int k)
{
    __shared__ __align__(16) float fr[96 * FRS];
    __shared__ __align__(16) float kr[784];
    __shared__ float dg[784];
    __shared__ __align__(16) float cv[4][69 * CVS];
    __shared__ float red[32];

    const int t = threadIdx.x;
    const int ib = blockIdx.x;

    if (t < 784) {
        kr[t] = ck[((size_t)ib * KKC + k) * 784 + t];
        if (k > 0) dg[t] = ck[((size_t)ib * KKC + (k - 1)) * 784 + t];
    }
    float zx = 0.f, zy = 0.f;
    if (k > 0) { zx = z_cur[ib * 2]; zy = z_cur[ib * 2 + 1]; }
    __syncthreads();

    const float* src = (k < 2)
        ? frames + ((size_t)ib * TT + *tsp) * 9216
        : frameL + (size_t)ib * 9216;
    const float scale = 96.f / 28.f;
    for (int p = t; p < 9216; p += 1024) {
        int r = p / 96, c = p - r * 96;
        float val = src[p];
        if (k > 0) {
            float oci = (2.f * r + 1.f) / 96.f - 1.f;
            float ocj = (2.f * c + 1.f) / 96.f - 1.f;
            float py = ((scale * (oci - zy) + 1.f) * 28.f - 1.f) * 0.5f;
            float px = ((scale * (ocj - zx) + 1.f) * 28.f - 1.f) * 0.5f;
            float py0f = floorf(py), px0f = floorf(px);
            float fy = py - py0f, fx = px - px0f;
            int y0 = (int)py0f, x0 = (int)px0f;
            int y1 = y0 + 1, x1 = x0 + 1;
            float wy0 = (y0 >= 0 && y0 < DPD) ? 1.f - fy : 0.f;
            float wy1 = (y1 >= 0 && y1 < DPD) ? fy : 0.f;
            float wx0 = (x0 >= 0 && x0 < DPD) ? 1.f - fx : 0.f;
            float wx1 = (x1 >= 0 && x1 < DPD) ? fx : 0.f;
            int y0c = min(max(y0, 0), DPD - 1), y1c = min(max(y1, 0), DPD - 1);
            int x0c = min(max(x0, 0), DPD - 1), x1c = min(max(x1, 0), DPD - 1);
            float tmp0 = wy0 * dg[y0c * DPD + x0c] + wy1 * dg[y1c * DPD + x0c];
            float tmp1 = wy0 * dg[y0c * DPD + x1c] + wy1 * dg[y1c * DPD + x1c];
            val -= wx0 * tmp0 + wx1 * tmp1;
        }
        fr[r * FRS + c] = val;
        if (k == 1) frameL[(size_t)ib * 9216 + p] = val;
    }
    if (t < 384) fr[(t >> 2) * FRS + 96 + (t & 3)] = 0.f;  // zero pad cols 96..99
    __syncthreads();

    if (t < 828) {
        const int q    = t / 207;
        const int rem  = t - q * 207;
        const int oy   = rem / 3;
        const int tile = rem - oy * 3;
        const int ox0  = tile * 24;
        const int dy0  = q * 7;

        float acc[24];
        #pragma unroll
        for (int j = 0; j < 24; ++j) acc[j] = 0.f;

        #pragma unroll 1
        for (int dd = 0; dd < 7; ++dd) {
            const int dy = dy0 + dd;
            const float* frow = &fr[(oy + dy) * FRS + ox0];
            const float* krow = &kr[dy * 28];
            float w[52];
            #pragma unroll
            for (int u = 0; u < 13; ++u) {
                float4 v = *(const float4*)(frow + 4 * u);
                w[4*u] = v.x; w[4*u+1] = v.y; w[4*u+2] = v.z; w[4*u+3] = v.w;
            }
            #pragma unroll
            for (int d = 0; d < 28; d += 4) {
                float4 kv = *(const float4*)(krow + d);
                #pragma unroll
                for (int j = 0; j < 24; ++j) {
                    acc[j] = fmaf(w[d + j],     kv.x, acc[j]);
                    acc[j] = fmaf(w[d + j + 1], kv.y, acc[j]);
                    acc[j] = fmaf(w[d + j + 2], kv.z, acc[j]);
                    acc[j] = fmaf(w[d + j + 3], kv.w, acc[j]);
                }
            }
        }
        float* cvq = &cv[q][oy * CVS + ox0];
        #pragma unroll
        for (int u = 0; u < 6; ++u) {
            float4 v = make_float4(acc[4*u], acc[4*u+1], acc[4*u+2], acc[4*u+3]);
            *(float4*)(cvq + 4 * u) = v;
        }
    }
    __syncthreads();

    // merge quarters + block max (stride-72 slabs; skip pad cols)
    float m = -INFINITY;
    for (int p = t; p < 69 * CVS; p += 1024) {
        int ox = p - (p / CVS) * CVS;
        if (ox < CPD) {
            float v = cv[0][p] + cv[1][p] + cv[2][p] + cv[3][p];
            cv[0][p] = v;
            m = fmaxf(m, v);
        }
    }
    #pragma unroll
    for (int off = 32; off > 0; off >>= 1) m = fmaxf(m, __shfl_down(m, off, 64));
    int lane = t & 63, wid = t >> 6;
    if (lane == 0) red[wid] = m;
    __syncthreads();
    m = red[0];
    #pragma unroll
    for (int i = 1; i < 16; ++i) m = fmaxf(m, red[i]);

    float s = 0.f;
    ushort* eo = e_buf + (size_t)ib * KPAD;
    for (int p = t; p < 69 * CVS; p += 1024) {
        int oy = p / CVS;
        int ox = p - oy * CVS;
        if (ox < CPD) {
            float ev = __expf(cv[0][p] - m);
            __hip_bfloat16 h = __float2bfloat16(ev);
            eo[oy * CPD + ox] = *reinterpret_cast<ushort*>(&h);
            s += ev;
        }
    }
    #pragma unroll
    for (int off = 32; off > 0; off >>= 1) s += __shfl_down(s, off, 64);
    if (lane == 0) red[16 + wid] = s;
    __syncthreads();
    if (t == 0) {
        float tot = 0.f;
        #pragma unroll
        for (int i = 0; i < 16; ++i) tot += red[16 + i];
        inv_denom[ib] = 1.0f / tot;
    }
    if (t < KPAD - NPD) eo[NPD + t] = 0;   // zero k-padding
}

// ---------------------------------------------------------------------------
// Cpart[z] = E(256xKPAD bf16) @ W1T^T (KPADx512 bf16), split-K=15, MFMA.
__global__ __launch_bounds__(256) void gemm1_mfma(
    const ushort* __restrict__ E, const ushort* __restrict__ W1T,
    float* __restrict__ Cpart)
{
    __shared__ __align__(16) ushort As[64][56];   // [m][k]
    __shared__ __align__(16) ushort Bs[64][56];   // [n][k]

    const int t  = threadIdx.x;
    const int m0 = blockIdx.x * 64;   // 4
    const int n0 = blockIdx.y * 64;   // 8
    const int z  = blockIdx.z;        // 15
    const int step0 = z * 10;
    const int nstep = min(10, 149 - step0);   // z=14 -> 9

    const int r = t >> 2;             // 0..63
    const int c = t & 3;              // 0..3
    const int l = t & 63;
    const int w = t >> 6;             // wave 0..3
    const int lm = l & 15;
    const int kb = l >> 4;            // 0..3

    f32x4 zero = {0.f, 0.f, 0.f, 0.f};
    f32x4 acc[4] = {zero, zero, zero, zero};

    const ushort* eA = E   + (size_t)(m0 + r) * KPAD + c * 8;
    const ushort* eB = W1T + (size_t)(n0 + r) * KPAD + c * 8;

    int k0 = step0 * 32;
    float4 av = *(const float4*)(eA + k0);
    float4 bv = *(const float4*)(eB + k0);

    for (int s = 0; s < nstep; ++s) {
        *(float4*)&As[r][c * 8] = av;
        *(float4*)&Bs[r][c * 8] = bv;
        __syncthreads();
        if (s + 1 < nstep) {
            int kn = (step0 + s + 1) * 32;
            av = *(const float4*)(eA + kn);
            bv = *(const float4*)(eB + kn);
        }
        bf16x8 a = *(const bf16x8*)&As[w * 16 + lm][kb * 8];
        #pragma unroll
        for (int j = 0; j < 4; ++j) {
            bf16x8 b = *(const bf16x8*)&Bs[j * 16 + lm][kb * 8];
            acc[j] = __builtin_amdgcn_mfma_f32_16x16x32_bf16(a, b, acc[j], 0, 0, 0);
        }
        __syncthreads();
    }

    // C/D layout: col = lane&15 (n), row = (lane>>4)*4 + reg (m)
    const int mrow = m0 + w * 16 + kb * 4;
    #pragma unroll
    for (int j = 0; j < 4; ++j) {
        int n = n0 + j * 16 + lm;
        #pragma unroll
        for (int rg = 0; rg < 4; ++rg)
            Cpart[((size_t)z * SBN + mrow + rg) * HD + n] = acc[j][rg];
    }
}

// ---------------------------------------------------------------------------
// Fused MLP: h = relu(sum_z Cpart * inv_den + b1); hidden (bf16, K-contiguous
// WhidT rows, 16B vector loads); heads. 256 blocks x 512 threads, 1 image.
__global__ __launch_bounds__(512) void mlp_fused(
    const float* __restrict__ Cpart, const float* __restrict__ inv_denom,
    const float* __restrict__ b1, const ushort* __restrict__ WhidT,
    const float* __restrict__ bm1, const float* __restrict__ bs1,
    const float* __restrict__ Wm2, const float* __restrict__ bm2,
    const float* __restrict__ Ws2, const float* __restrict__ bs2,
    const float* __restrict__ eps, float* __restrict__ out,
    float* __restrict__ z_cur, int k)
{
    __shared__ float hsh[HD];
    __shared__ float h2[2][256];       // [head][col]
    __shared__ float res_sh[2][2];     // [zd][head]

    const int t = threadIdx.x;
    const int ib = blockIdx.x;

    {
        float s = 0.f;
        #pragma unroll
        for (int z = 0; z < SPLITK; ++z)
            s += Cpart[((size_t)z * SBN + ib) * HD + t];
        hsh[t] = fmaxf(fmaf(s, inv_denom[ib], b1[t]), 0.f);
    }
    __syncthreads();

    {
        int head = t >> 8, col = t & 255;
        const uint4* Wr = (const uint4*)(WhidT + (size_t)(head * 256 + col) * 512);
        float bias = head ? bs1[col] : bm1[col];
        float a = 0.f;
        #pragma unroll 8
        for (int u = 0; u < 64; ++u) {
            uint4 wv = Wr[u];
            const float* hp = &hsh[u * 8];
            a = fmaf(hp[0], bf2f_lo(wv.x), a);
            a = fmaf(hp[1], bf2f_hi(wv.x), a);
            a = fmaf(hp[2], bf2f_lo(wv.y), a);
            a = fmaf(hp[3], bf2f_hi(wv.y), a);
            a = fmaf(hp[4], bf2f_lo(wv.z), a);
            a = fmaf(hp[5], bf2f_hi(wv.z), a);
            a = fmaf(hp[6], bf2f_lo(wv.w), a);
            a = fmaf(hp[7], bf2f_hi(wv.w), a);
        }
        h2[head][col] = fmaxf(a + bias, 0.f);
    }
    __syncthreads();

    {
        int w = t >> 6, l = t & 63;
        if (w < 4) {
            int zd = (w >> 1) & 1, head = w & 1;
            const float* W2 = head ? Ws2 : Wm2;
            float a = 0.f;
            #pragma unroll
            for (int u = 0; u < 4; ++u) {
                int i = l + u * 64;
                a = fmaf(h2[head][i], W2[i * 2 + zd], a);
            }
            #pragma unroll
            for (int off = 32; off > 0; off >>= 1) a += __shfl_down(a, off, 64);
            if (l == 0) {
                float r = head ? __expf(a + bs2[zd]) : tanhf(a + bm2[zd]);
                res_sh[zd][head] = r;
            }
        }
    }
    __syncthreads();
    if (t < 2) {
        int zd = t;
        float mean = res_sh[zd][0];
        float stdv = res_sh[zd][1];
        float ev = eps[(size_t)ib * 6 + k * 2 + zd];
        float z = fmaf(stdv, ev, mean);
        int oidx = ib * 6 + k * 2 + zd;
        out[oidx]        = mean;   // q_mean
        out[1536 + oidx] = stdv;   // q_std
        out[3072 + oidx] = z;      // z_where
        z_cur[ib * 2 + zd] = z;
    }
}

// ---------------------------------------------------------------------------
extern "C" void kernel_launch(void* const* d_in, const int* in_sizes, int n_in,
                              void* d_out, int out_size, void* d_ws, size_t ws_size,
                              hipStream_t stream)
{
    const float* frames = (const float*)d_in[0];
    const float* ck     = (const float*)d_in[1];
    const float* eps    = (const float*)d_in[2];
    const float* W1     = (const float*)d_in[3];
    const float* b1     = (const float*)d_in[4];
    const float* Wm1    = (const float*)d_in[5];
    const float* bm1    = (const float*)d_in[6];
    const float* Wm2    = (const float*)d_in[7];
    const float* bm2    = (const float*)d_in[8];
    const float* Ws1    = (const float*)d_in[9];
    const float* bs1    = (const float*)d_in[10];
    const float* Ws2    = (const float*)d_in[11];
    const float* bs2    = (const float*)d_in[12];
    const int*   tsp    = (const int*)d_in[13];
    float* out = (float*)d_out;

    float* frameL  = (float*)d_ws;                   // 2359296 f
    float* Cpart   = frameL + 2359296;               // 15*256*512 = 1966080 f
    float* inv_den = Cpart + 1966080;                // 256 f
    float* z_cur   = inv_den + 256;                  // 512 f
    ushort* e_buf  = (ushort*)(z_cur + 512);         // 256*KPAD
    ushort* W1T    = e_buf + (size_t)SBN * KPAD;     // 512*KPAD
    ushort* WhidT  = W1T + (size_t)HD * KPAD;        // 512*512

    w1t_kernel<<<dim3(75, 8), 256, 0, stream>>>(W1, W1T);
    whidt_kernel<<<dim3(8, 8), 256, 0, stream>>>(Wm1, Ws1, WhidT);

    for (int k = 0; k < KKC; ++k) {
        conv_softmax_kernel<<<256, 1024, 0, stream>>>(
            frames, tsp, frameL, ck, z_cur, e_buf, inv_den, k);
        gemm1_mfma<<<dim3(4, 8, SPLITK), 256, 0, stream>>>(e_buf, W1T, Cpart);
        mlp_fused<<<256, 512, 0, stream>>>(Cpart, inv_den, b1, WhidT,
                                           bm1, bs1, Wm2, bm2, Ws2, bs2,
                                           eps, out, z_cur, k);
    }
}

// Round 6
// 313.461 us; speedup vs baseline: 2.1691x; 1.0068x over previous
//
#include <hip/hip_runtime.h>
#include <hip/hip_bf16.h>
#include <math.h>

// Problem constants
#define FPD 96      // frame size
#define DPD 28      // digit/kernel size
#define CPD 69      // FPD - DPD + 1
#define NPD 4761    // CPD*CPD
#define KKC 3       // K iterations
#define SBN 256     // S*B images
#define TT 8        // T
#define HD 512      // H
#define ZDD 2
#define KPAD 4768   // 149*32, padded K for MFMA GEMM
#define SPLITK 15
#define FRS 100     // frame LDS row stride
#define CVS 72      // cv slab row stride (b128-aligned output writes)

typedef __attribute__((ext_vector_type(8))) short bf16x8;
typedef __attribute__((ext_vector_type(4))) float f32x4;

__device__ __forceinline__ float bf2f_lo(unsigned int u) {
    union { unsigned int i; float f; } v; v.i = u << 16; return v.f;
}
__device__ __forceinline__ float bf2f_hi(unsigned int u) {
    union { unsigned int i; float f; } v; v.i = u & 0xffff0000u; return v.f;
}

// ---------------------------------------------------------------------------
// Weight prep (one dispatch): blocks 0..599 build W1T (bf16, KPAD-padded,
// [n][k]); blocks 600..663 build WhidT ([head*256+col][i], i contiguous).
__global__ __launch_bounds__(256) void wprep_kernel(
    const float* __restrict__ W1, const float* __restrict__ Wm1,
    const float* __restrict__ Ws1,
    ushort* __restrict__ W1T, ushort* __restrict__ WhidT)
{
    __shared__ ushort tile[64][65];
    const int t = threadIdx.x;
    const int ln = t & 63;
    const int lr = t >> 6;             // 0..3
    const int b = blockIdx.x;

    if (b < 600) {
        const int k0 = (b % 75) * 64;
        const int n0 = (b / 75) * 64;
        #pragma unroll
        for (int i = 0; i < 16; ++i) {
            int kk = k0 + lr + i * 4;
            float v = (kk < NPD) ? W1[(size_t)kk * HD + n0 + ln] : 0.f;
            __hip_bfloat16 h = __float2bfloat16(v);
            tile[lr + i * 4][ln] = *reinterpret_cast<ushort*>(&h);
        }
        __syncthreads();
        #pragma unroll
        for (int i = 0; i < 16; ++i) {
            int nn = lr + i * 4;
            int kk = k0 + ln;
            if (kk < KPAD)
                W1T[(size_t)(n0 + nn) * KPAD + kk] = tile[ln][nn];
        }
    } else {
        const int bb = b - 600;
        const int i0 = (bb & 7) * 64;
        const int r0 = (bb >> 3) * 64;
        #pragma unroll
        for (int rep = 0; rep < 16; ++rep) {
            int i = i0 + lr + rep * 4;
            int r = r0 + ln;
            const float* src = (r >= 256) ? Ws1 : Wm1;
            float v = src[(size_t)i * 256 + (r & 255)];
            __hip_bfloat16 h = __float2bfloat16(v);
            tile[lr + rep * 4][ln] = *reinterpret_cast<ushort*>(&h);
        }
        __syncthreads();
        #pragma unroll
        for (int rep = 0; rep < 16; ++rep) {
            int r = r0 + lr + rep * 4;
            WhidT[(size_t)r * 512 + i0 + ln] = tile[ln][lr + rep * 4];
        }
    }
}

// ---------------------------------------------------------------------------
// Conv + fused recon-subtract + softmax-exp (bf16 out).
// One block (1024 threads, pinned 1 block/CU -> 128 VGPR budget) per image.
// Tasks: 69 oy x 3 tiles(24 wide) x 4 dy-quarters = 828.
__global__ __launch_bounds__(1024, 4) void conv_softmax_kernel(
    const float* __restrict__ frames, const int* __restrict__ tsp,
    float* __restrict__ frameL, const float* __restrict__ ck,
    const float* __restrict__ z_cur,
    ushort* __restrict__ e_buf, float* __restrict__ inv_denom, int k)
{
    __shared__ __align__(16) float fr[96 * FRS];
    __shared__ __align__(16) float kr[784];
    __shared__ float dg[784];
    __shared__ __align__(16) float cv[4][69 * CVS];
    __shared__ float red[32];

    const int t = threadIdx.x;
    const int ib = blockIdx.x;

    if (t < 784) {
        kr[t] = ck[((size_t)ib * KKC + k) * 784 + t];
        if (k > 0) dg[t] = ck[((size_t)ib * KKC + (k - 1)) * 784 + t];
    }
    float zx = 0.f, zy = 0.f;
    if (k > 0) { zx = z_cur[ib * 2]; zy = z_cur[ib * 2 + 1]; }
    __syncthreads();

    const float* src = (k < 2)
        ? frames + ((size_t)ib * TT + *tsp) * 9216
        : frameL + (size_t)ib * 9216;
    const float scale = 96.f / 28.f;
    for (int p = t; p < 9216; p += 1024) {
        int r = p / 96, c = p - r * 96;
        float val = src[p];
        if (k > 0) {
            float oci = (2.f * r + 1.f) / 96.f - 1.f;
            float ocj = (2.f * c + 1.f) / 96.f - 1.f;
            float py = ((scale * (oci - zy) + 1.f) * 28.f - 1.f) * 0.5f;
            float px = ((scale * (ocj - zx) + 1.f) * 28.f - 1.f) * 0.5f;
            float py0f = floorf(py), px0f = floorf(px);
            float fy = py - py0f, fx = px - px0f;
            int y0 = (int)py0f, x0 = (int)px0f;
            int y1 = y0 + 1, x1 = x0 + 1;
            float wy0 = (y0 >= 0 && y0 < DPD) ? 1.f - fy : 0.f;
            float wy1 = (y1 >= 0 && y1 < DPD) ? fy : 0.f;
            float wx0 = (x0 >= 0 && x0 < DPD) ? 1.f - fx : 0.f;
            float wx1 = (x1 >= 0 && x1 < DPD) ? fx : 0.f;
            int y0c = min(max(y0, 0), DPD - 1), y1c = min(max(y1, 0), DPD - 1);
            int x0c = min(max(x0, 0), DPD - 1), x1c = min(max(x1, 0), DPD - 1);
            float tmp0 = wy0 * dg[y0c * DPD + x0c] + wy1 * dg[y1c * DPD + x0c];
            float tmp1 = wy0 * dg[y0c * DPD + x1c] + wy1 * dg[y1c * DPD + x1c];
            val -= wx0 * tmp0 + wx1 * tmp1;
        }
        fr[r * FRS + c] = val;
        if (k == 1) frameL[(size_t)ib * 9216 + p] = val;
    }
    if (t < 384) fr[(t >> 2) * FRS + 96 + (t & 3)] = 0.f;  // zero pad cols 96..99
    __syncthreads();

    if (t < 828) {
        const int q    = t / 207;
        const int rem  = t - q * 207;
        const int oy   = rem / 3;
        const int tile = rem - oy * 3;
        const int ox0  = tile * 24;
        const int dy0  = q * 7;

        float acc[24];
        #pragma unroll
        for (int j = 0; j < 24; ++j) acc[j] = 0.f;

        #pragma unroll 1
        for (int dd = 0; dd < 7; ++dd) {
            const int dy = dy0 + dd;
            const float* frow = &fr[(oy + dy) * FRS + ox0];
            const float* krow = &kr[dy * 28];
            float w[52];
            #pragma unroll
            for (int u = 0; u < 13; ++u) {
                float4 v = *(const float4*)(frow + 4 * u);
                w[4*u] = v.x; w[4*u+1] = v.y; w[4*u+2] = v.z; w[4*u+3] = v.w;
            }
            #pragma unroll
            for (int d = 0; d < 28; d += 4) {
                float4 kv = *(const float4*)(krow + d);
                #pragma unroll
                for (int j = 0; j < 24; ++j) {
                    acc[j] = fmaf(w[d + j],     kv.x, acc[j]);
                    acc[j] = fmaf(w[d + j + 1], kv.y, acc[j]);
                    acc[j] = fmaf(w[d + j + 2], kv.z, acc[j]);
                    acc[j] = fmaf(w[d + j + 3], kv.w, acc[j]);
                }
            }
        }
        float* cvq = &cv[q][oy * CVS + ox0];
        #pragma unroll
        for (int u = 0; u < 6; ++u) {
            float4 v = make_float4(acc[4*u], acc[4*u+1], acc[4*u+2], acc[4*u+3]);
            *(float4*)(cvq + 4 * u) = v;
        }
    }
    __syncthreads();

    // merge quarters + block max (stride-72 slabs; skip pad cols)
    float m = -INFINITY;
    for (int p = t; p < 69 * CVS; p += 1024) {
        int ox = p - (p / CVS) * CVS;
        if (ox < CPD) {
            float v = cv[0][p] + cv[1][p] + cv[2][p] + cv[3][p];
            cv[0][p] = v;
            m = fmaxf(m, v);
        }
    }
    #pragma unroll
    for (int off = 32; off > 0; off >>= 1) m = fmaxf(m, __shfl_down(m, off, 64));
    int lane = t & 63, wid = t >> 6;
    if (lane == 0) red[wid] = m;
    __syncthreads();
    m = red[0];
    #pragma unroll
    for (int i = 1; i < 16; ++i) m = fmaxf(m, red[i]);

    float s = 0.f;
    ushort* eo = e_buf + (size_t)ib * KPAD;
    for (int p = t; p < 69 * CVS; p += 1024) {
        int oy = p / CVS;
        int ox = p - oy * CVS;
        if (ox < CPD) {
            float ev = __expf(cv[0][p] - m);
            __hip_bfloat16 h = __float2bfloat16(ev);
            eo[oy * CPD + ox] = *reinterpret_cast<ushort*>(&h);
            s += ev;
        }
    }
    #pragma unroll
    for (int off = 32; off > 0; off >>= 1) s += __shfl_down(s, off, 64);
    if (lane == 0) red[16 + wid] = s;
    __syncthreads();
    if (t == 0) {
        float tot = 0.f;
        #pragma unroll
        for (int i = 0; i < 16; ++i) tot += red[16 + i];
        inv_denom[ib] = 1.0f / tot;
    }
    if (t < KPAD - NPD) eo[NPD + t] = 0;   // zero k-padding
}

// ---------------------------------------------------------------------------
// Cpart[z] = E(256xKPAD bf16) @ W1T^T (KPADx512 bf16), split-K=15, MFMA.
__global__ __launch_bounds__(256) void gemm1_mfma(
    const ushort* __restrict__ E, const ushort* __restrict__ W1T,
    float* __restrict__ Cpart)
{
    __shared__ __align__(16) ushort As[64][56];   // [m][k]
    __shared__ __align__(16) ushort Bs[64][56];   // [n][k]

    const int t  = threadIdx.x;
    const int m0 = blockIdx.x * 64;   // 4
    const int n0 = blockIdx.y * 64;   // 8
    const int z  = blockIdx.z;        // 15
    const int step0 = z * 10;
    const int nstep = min(10, 149 - step0);   // z=14 -> 9

    const int r = t >> 2;             // 0..63
    const int c = t & 3;              // 0..3
    const int l = t & 63;
    const int w = t >> 6;             // wave 0..3
    const int lm = l & 15;
    const int kb = l >> 4;            // 0..3

    f32x4 zero = {0.f, 0.f, 0.f, 0.f};
    f32x4 acc[4] = {zero, zero, zero, zero};

    const ushort* eA = E   + (size_t)(m0 + r) * KPAD + c * 8;
    const ushort* eB = W1T + (size_t)(n0 + r) * KPAD + c * 8;

    int k0 = step0 * 32;
    float4 av = *(const float4*)(eA + k0);
    float4 bv = *(const float4*)(eB + k0);

    for (int s = 0; s < nstep; ++s) {
        *(float4*)&As[r][c * 8] = av;
        *(float4*)&Bs[r][c * 8] = bv;
        __syncthreads();
        if (s + 1 < nstep) {
            int kn = (step0 + s + 1) * 32;
            av = *(const float4*)(eA + kn);
            bv = *(const float4*)(eB + kn);
        }
        bf16x8 a = *(const bf16x8*)&As[w * 16 + lm][kb * 8];
        #pragma unroll
        for (int j = 0; j < 4; ++j) {
            bf16x8 b = *(const bf16x8*)&Bs[j * 16 + lm][kb * 8];
            acc[j] = __builtin_amdgcn_mfma_f32_16x16x32_bf16(a, b, acc[j], 0, 0, 0);
        }
        __syncthreads();
    }

    // C/D layout: col = lane&15 (n), row = (lane>>4)*4 + reg (m)
    const int mrow = m0 + w * 16 + kb * 4;
    #pragma unroll
    for (int j = 0; j < 4; ++j) {
        int n = n0 + j * 16 + lm;
        #pragma unroll
        for (int rg = 0; rg < 4; ++rg)
            Cpart[((size_t)z * SBN + mrow + rg) * HD + n] = acc[j][rg];
    }
}

// ---------------------------------------------------------------------------
// Fused MLP: h = relu(sum_z Cpart * inv_den + b1); hidden (bf16, K-contiguous
// WhidT rows, 16B vector loads); heads. 256 blocks x 512 threads, 1 image.
__global__ __launch_bounds__(512) void mlp_fused(
    const float* __restrict__ Cpart, const float* __restrict__ inv_denom,
    const float* __restrict__ b1, const ushort* __restrict__ WhidT,
    const float* __restrict__ bm1, const float* __restrict__ bs1,
    const float* __restrict__ Wm2, const float* __restrict__ bm2,
    const float* __restrict__ Ws2, const float* __restrict__ bs2,
    const float* __restrict__ eps, float* __restrict__ out,
    float* __restrict__ z_cur, int k)
{
    __shared__ float hsh[HD];
    __shared__ float h2[2][256];       // [head][col]
    __shared__ float res_sh[2][2];     // [zd][head]

    const int t = threadIdx.x;
    const int ib = blockIdx.x;

    {
        float s = 0.f;
        #pragma unroll
        for (int z = 0; z < SPLITK; ++z)
            s += Cpart[((size_t)z * SBN + ib) * HD + t];
        hsh[t] = fmaxf(fmaf(s, inv_denom[ib], b1[t]), 0.f);
    }
    __syncthreads();

    {
        int head = t >> 8, col = t & 255;
        const uint4* Wr = (const uint4*)(WhidT + (size_t)(head * 256 + col) * 512);
        float bias = head ? bs1[col] : bm1[col];
        float a = 0.f;
        #pragma unroll 8
        for (int u = 0; u < 64; ++u) {
            uint4 wv = Wr[u];
            const float* hp = &hsh[u * 8];
            a = fmaf(hp[0], bf2f_lo(wv.x), a);
            a = fmaf(hp[1], bf2f_hi(wv.x), a);
            a = fmaf(hp[2], bf2f_lo(wv.y), a);
            a = fmaf(hp[3], bf2f_hi(wv.y), a);
            a = fmaf(hp[4], bf2f_lo(wv.z), a);
            a = fmaf(hp[5], bf2f_hi(wv.z), a);
            a = fmaf(hp[6], bf2f_lo(wv.w), a);
            a = fmaf(hp[7], bf2f_hi(wv.w), a);
        }
        h2[head][col] = fmaxf(a + bias, 0.f);
    }
    __syncthreads();

    {
        int w = t >> 6, l = t & 63;
        if (w < 4) {
            int zd = (w >> 1) & 1, head = w & 1;
            const float* W2 = head ? Ws2 : Wm2;
            float a = 0.f;
            #pragma unroll
            for (int u = 0; u < 4; ++u) {
                int i = l + u * 64;
                a = fmaf(h2[head][i], W2[i * 2 + zd], a);
            }
            #pragma unroll
            for (int off = 32; off > 0; off >>= 1) a += __shfl_down(a, off, 64);
            if (l == 0) {
                float r = head ? __expf(a + bs2[zd]) : tanhf(a + bm2[zd]);
                res_sh[zd][head] = r;
            }
        }
    }
    __syncthreads();
    if (t < 2) {
        int zd = t;
        float mean = res_sh[zd][0];
        float stdv = res_sh[zd][1];
        float ev = eps[(size_t)ib * 6 + k * 2 + zd];
        float z = fmaf(stdv, ev, mean);
        int oidx = ib * 6 + k * 2 + zd;
        out[oidx]        = mean;   // q_mean
        out[1536 + oidx] = stdv;   // q_std
        out[3072 + oidx] = z;      // z_where
        z_cur[ib * 2 + zd] = z;
    }
}

// ---------------------------------------------------------------------------
extern "C" void kernel_launch(void* const* d_in, const int* in_sizes, int n_in,
                              void* d_out, int out_size, void* d_ws, size_t ws_size,
                              hipStream_t stream)
{
    const float* frames = (const float*)d_in[0];
    const float* ck     = (const float*)d_in[1];
    const float* eps    = (const float*)d_in[2];
    const float* W1     = (const float*)d_in[3];
    const float* b1     = (const float*)d_in[4];
    const float* Wm1    = (const float*)d_in[5];
    const float* bm1    = (const float*)d_in[6];
    const float* Wm2    = (const float*)d_in[7];
    const float* bm2    = (const float*)d_in[8];
    const float* Ws1    = (const float*)d_in[9];
    const float* bs1    = (const float*)d_in[10];
    const float* Ws2    = (const float*)d_in[11];
    const float* bs2    = (const float*)d_in[12];
    const int*   tsp    = (const int*)d_in[13];
    float* out = (float*)d_out;

    float* frameL  = (float*)d_ws;                   // 2359296 f
    float* Cpart   = frameL + 2359296;               // 15*256*512 = 1966080 f
    float* inv_den = Cpart + 1966080;                // 256 f
    float* z_cur   = inv_den + 256;                  // 512 f
    ushort* e_buf  = (ushort*)(z_cur + 512);         // 256*KPAD
    ushort* W1T    = e_buf + (size_t)SBN * KPAD;     // 512*KPAD
    ushort* WhidT  = W1T + (size_t)HD * KPAD;        // 512*512

    wprep_kernel<<<664, 256, 0, stream>>>(W1, Wm1, Ws1, W1T, WhidT);

    for (int k = 0; k < KKC; ++k) {
        conv_softmax_kernel<<<256, 1024, 0, stream>>>(
            frames, tsp, frameL, ck, z_cur, e_buf, inv_den, k);
        gemm1_mfma<<<dim3(4, 8, SPLITK), 256, 0, stream>>>(e_buf, W1T, Cpart);
        mlp_fused<<<256, 512, 0, stream>>>(Cpart, inv_den, b1, WhidT,
                                           bm1, bs1, Wm2, bm2, Ws2, bs2,
                                           eps, out, z_cur, k);
    }
}

// Round 7
// 301.273 us; speedup vs baseline: 2.2569x; 1.0405x over previous
//
#include <hip/hip_runtime.h>
#include <hip/hip_bf16.h>
#include <math.h>

// Problem constants
#define FPD 96      // frame size
#define DPD 28      // digit/kernel size
#define CPD 69      // FPD - DPD + 1
#define NPD 4761    // CPD*CPD
#define KKC 3       // K iterations
#define SBN 256     // S*B images
#define TT 8        // T
#define HD 512      // H
#define ZDD 2
#define KPAD 4768   // 149*32, padded K for MFMA GEMM
#define SPLITK 15
#define FRSH 104    // frame LDS row stride (halfs): 52 words, mod32=20 -> conflict-free
#define CVS 76      // cv slab row stride (floats): mod32=12 -> conflict-free

typedef __attribute__((ext_vector_type(8))) short bf16x8;
typedef __attribute__((ext_vector_type(4))) float f32x4;
typedef _Float16 half_t;
typedef __attribute__((ext_vector_type(2))) _Float16 half2_t;

__device__ __forceinline__ float bf2f_lo(unsigned int u) {
    union { unsigned int i; float f; } v; v.i = u << 16; return v.f;
}
__device__ __forceinline__ float bf2f_hi(unsigned int u) {
    union { unsigned int i; float f; } v; v.i = u & 0xffff0000u; return v.f;
}
__device__ __forceinline__ half2_t u2h(unsigned int u) {
    union { unsigned int i; half2_t h; } v; v.i = u; return v.h;
}

// ---------------------------------------------------------------------------
// Weight prep (one dispatch): blocks 0..599 build W1T (bf16, KPAD-padded,
// [n][k]); blocks 600..663 build WhidT ([head*256+col][i], i contiguous).
__global__ __launch_bounds__(256) void wprep_kernel(
    const float* __restrict__ W1, const float* __restrict__ Wm1,
    const float* __restrict__ Ws1,
    ushort* __restrict__ W1T, ushort* __restrict__ WhidT)
{
    __shared__ ushort tile[64][65];
    const int t = threadIdx.x;
    const int ln = t & 63;
    const int lr = t >> 6;             // 0..3
    const int b = blockIdx.x;

    if (b < 600) {
        const int k0 = (b % 75) * 64;
        const int n0 = (b / 75) * 64;
        #pragma unroll
        for (int i = 0; i < 16; ++i) {
            int kk = k0 + lr + i * 4;
            float v = (kk < NPD) ? W1[(size_t)kk * HD + n0 + ln] : 0.f;
            __hip_bfloat16 h = __float2bfloat16(v);
            tile[lr + i * 4][ln] = *reinterpret_cast<ushort*>(&h);
        }
        __syncthreads();
        #pragma unroll
        for (int i = 0; i < 16; ++i) {
            int nn = lr + i * 4;
            int kk = k0 + ln;
            if (kk < KPAD)
                W1T[(size_t)(n0 + nn) * KPAD + kk] = tile[ln][nn];
        }
    } else {
        const int bb = b - 600;
        const int i0 = (bb & 7) * 64;
        const int r0 = (bb >> 3) * 64;
        #pragma unroll
        for (int rep = 0; rep < 16; ++rep) {
            int i = i0 + lr + rep * 4;
            int r = r0 + ln;
            const float* src = (r >= 256) ? Ws1 : Wm1;
            float v = src[(size_t)i * 256 + (r & 255)];
            __hip_bfloat16 h = __float2bfloat16(v);
            tile[lr + rep * 4][ln] = *reinterpret_cast<ushort*>(&h);
        }
        __syncthreads();
        #pragma unroll
        for (int rep = 0; rep < 16; ++rep) {
            int r = r0 + lr + rep * 4;
            WhidT[(size_t)r * 512 + i0 + ln] = tile[ln][lr + rep * 4];
        }
    }
}

// ---------------------------------------------------------------------------
// Conv (f16 dot2) + fused recon-subtract + softmax-exp (bf16 out).
// One block (1024 threads) per image. Tasks: 4 dy-quarters x 3 tiles(24 wide)
// x 69 oy, oy-innermost so consecutive lanes hit distinct LDS bank quads.
// Inner product via v_dot2_f32_f16 (2 MACs/inst, f32 accumulate); odd outputs
// use a 1-half-shifted window built with alignbit.
__global__ __launch_bounds__(1024, 4) void conv_softmax_kernel(
    const float* __restrict__ frames, const int* __restrict__ tsp,
    float* __restrict__ frameL, const float* __restrict__ ck,
    const float* __restrict__ z_cur,
    ushort* __restrict__ e_buf, float* __restrict__ inv_denom, int k)
{
    __shared__ __align__(16) half_t fr[96 * FRSH];
    __shared__ __align__(16) half_t kr[28 * 32];   // rows padded to 32 halfs
    __shared__ float dg[784];
    __shared__ __align__(16) float cv[4][69 * CVS];
    __shared__ float red[32];

    const int t = threadIdx.x;
    const int ib = blockIdx.x;

    if (t < 28 * 32) {
        int dy = t >> 5, dx = t & 31;
        float v = (dx < 28) ? ck[((size_t)ib * KKC + k) * 784 + dy * 28 + dx] : 0.f;
        kr[t] = (half_t)v;
    }
    if (k > 0 && t < 784) dg[t] = ck[((size_t)ib * KKC + (k - 1)) * 784 + t];
    float zx = 0.f, zy = 0.f;
    if (k > 0) { zx = z_cur[ib * 2]; zy = z_cur[ib * 2 + 1]; }
    __syncthreads();

    const float* src = (k < 2)
        ? frames + ((size_t)ib * TT + *tsp) * 9216
        : frameL + (size_t)ib * 9216;
    const float scale = 96.f / 28.f;
    for (int p = t; p < 9216; p += 1024) {
        int r = p / 96, c = p - r * 96;
        float val = src[p];
        if (k > 0) {
            float oci = (2.f * r + 1.f) / 96.f - 1.f;
            float ocj = (2.f * c + 1.f) / 96.f - 1.f;
            float py = ((scale * (oci - zy) + 1.f) * 28.f - 1.f) * 0.5f;
            float px = ((scale * (ocj - zx) + 1.f) * 28.f - 1.f) * 0.5f;
            float py0f = floorf(py), px0f = floorf(px);
            float fy = py - py0f, fx = px - px0f;
            int y0 = (int)py0f, x0 = (int)px0f;
            int y1 = y0 + 1, x1 = x0 + 1;
            float wy0 = (y0 >= 0 && y0 < DPD) ? 1.f - fy : 0.f;
            float wy1 = (y1 >= 0 && y1 < DPD) ? fy : 0.f;
            float wx0 = (x0 >= 0 && x0 < DPD) ? 1.f - fx : 0.f;
            float wx1 = (x1 >= 0 && x1 < DPD) ? fx : 0.f;
            int y0c = min(max(y0, 0), DPD - 1), y1c = min(max(y1, 0), DPD - 1);
            int x0c = min(max(x0, 0), DPD - 1), x1c = min(max(x1, 0), DPD - 1);
            float tmp0 = wy0 * dg[y0c * DPD + x0c] + wy1 * dg[y1c * DPD + x0c];
            float tmp1 = wy0 * dg[y0c * DPD + x1c] + wy1 * dg[y1c * DPD + x1c];
            val -= wx0 * tmp0 + wx1 * tmp1;
        }
        fr[r * FRSH + c] = (half_t)val;
        if (k == 1) frameL[(size_t)ib * 9216 + p] = val;
    }
    if (t < 96 * 8) fr[(t >> 3) * FRSH + 96 + (t & 7)] = (half_t)0.f; // pad cols
    __syncthreads();

    if (t < 828) {
        const int q    = t / 207;
        const int rem  = t - q * 207;
        const int tile = rem / 69;
        const int oy   = rem - tile * 69;
        const int ox0  = tile * 24;
        const int dy0  = q * 7;

        float acc[24];
        #pragma unroll
        for (int j = 0; j < 24; ++j) acc[j] = 0.f;

        #pragma unroll 1
        for (int dd = 0; dd < 7; ++dd) {
            const int dy = dy0 + dd;
            const unsigned int* frow = (const unsigned int*)&fr[(oy + dy) * FRSH + ox0];
            const unsigned int* krow = (const unsigned int*)&kr[dy * 32];
            unsigned int W[28], K[16], V[25];
            #pragma unroll
            for (int u = 0; u < 7; ++u) {
                uint4 v = *(const uint4*)(frow + 4 * u);
                W[4*u] = v.x; W[4*u+1] = v.y; W[4*u+2] = v.z; W[4*u+3] = v.w;
            }
            #pragma unroll
            for (int u = 0; u < 4; ++u) {
                uint4 v = *(const uint4*)(krow + 4 * u);
                K[4*u] = v.x; K[4*u+1] = v.y; K[4*u+2] = v.z; K[4*u+3] = v.w;
            }
            #pragma unroll
            for (int i = 0; i < 25; ++i)
                V[i] = (W[i] >> 16) | (W[i + 1] << 16);
            #pragma unroll
            for (int m = 0; m < 12; ++m) {
                float ae = acc[2*m], ao = acc[2*m+1];
                #pragma unroll
                for (int i = 0; i < 14; ++i) {
                    ae = __builtin_amdgcn_fdot2(u2h(W[m + i]), u2h(K[i]), ae, false);
                    ao = __builtin_amdgcn_fdot2(u2h(V[m + i]), u2h(K[i]), ao, false);
                }
                acc[2*m] = ae; acc[2*m+1] = ao;
            }
        }
        float* cvq = &cv[q][oy * CVS + ox0];
        #pragma unroll
        for (int u = 0; u < 6; ++u) {
            float4 v = make_float4(acc[4*u], acc[4*u+1], acc[4*u+2], acc[4*u+3]);
            *(float4*)(cvq + 4 * u) = v;
        }
    }
    __syncthreads();

    // merge quarters + block max (stride-76 slabs; skip pad cols)
    float m = -INFINITY;
    for (int p = t; p < 69 * CVS; p += 1024) {
        int ox = p - (p / CVS) * CVS;
        if (ox < CPD) {
            float v = cv[0][p] + cv[1][p] + cv[2][p] + cv[3][p];
            cv[0][p] = v;
            m = fmaxf(m, v);
        }
    }
    #pragma unroll
    for (int off = 32; off > 0; off >>= 1) m = fmaxf(m, __shfl_down(m, off, 64));
    int lane = t & 63, wid = t >> 6;
    if (lane == 0) red[wid] = m;
    __syncthreads();
    m = red[0];
    #pragma unroll
    for (int i = 1; i < 16; ++i) m = fmaxf(m, red[i]);

    float s = 0.f;
    ushort* eo = e_buf + (size_t)ib * KPAD;
    for (int p = t; p < 69 * CVS; p += 1024) {
        int oy = p / CVS;
        int ox = p - oy * CVS;
        if (ox < CPD) {
            float ev = __expf(cv[0][p] - m);
            __hip_bfloat16 h = __float2bfloat16(ev);
            eo[oy * CPD + ox] = *reinterpret_cast<ushort*>(&h);
            s += ev;
        }
    }
    #pragma unroll
    for (int off = 32; off > 0; off >>= 1) s += __shfl_down(s, off, 64);
    if (lane == 0) red[16 + wid] = s;
    __syncthreads();
    if (t == 0) {
        float tot = 0.f;
        #pragma unroll
        for (int i = 0; i < 16; ++i) tot += red[16 + i];
        inv_denom[ib] = 1.0f / tot;
    }
    if (t < KPAD - NPD) eo[NPD + t] = 0;   // zero k-padding
}

// ---------------------------------------------------------------------------
// Cpart[z] = E(256xKPAD bf16) @ W1T^T (KPADx512 bf16), split-K=15, MFMA.
__global__ __launch_bounds__(256) void gemm1_mfma(
    const ushort* __restrict__ E, const ushort* __restrict__ W1T,
    float* __restrict__ Cpart)
{
    __shared__ __align__(16) ushort As[64][56];   // [m][k]
    __shared__ __align__(16) ushort Bs[64][56];   // [n][k]

    const int t  = threadIdx.x;
    const int m0 = blockIdx.x * 64;   // 4
    const int n0 = blockIdx.y * 64;   // 8
    const int z  = blockIdx.z;        // 15
    const int step0 = z * 10;
    const int nstep = min(10, 149 - step0);   // z=14 -> 9

    const int r = t >> 2;             // 0..63
    const int c = t & 3;              // 0..3
    const int l = t & 63;
    const int w = t >> 6;             // wave 0..3
    const int lm = l & 15;
    const int kb = l >> 4;            // 0..3

    f32x4 zero = {0.f, 0.f, 0.f, 0.f};
    f32x4 acc[4] = {zero, zero, zero, zero};

    const ushort* eA = E   + (size_t)(m0 + r) * KPAD + c * 8;
    const ushort* eB = W1T + (size_t)(n0 + r) * KPAD + c * 8;

    int k0 = step0 * 32;
    float4 av = *(const float4*)(eA + k0);
    float4 bv = *(const float4*)(eB + k0);

    for (int s = 0; s < nstep; ++s) {
        *(float4*)&As[r][c * 8] = av;
        *(float4*)&Bs[r][c * 8] = bv;
        __syncthreads();
        if (s + 1 < nstep) {
            int kn = (step0 + s + 1) * 32;
            av = *(const float4*)(eA + kn);
            bv = *(const float4*)(eB + kn);
        }
        bf16x8 a = *(const bf16x8*)&As[w * 16 + lm][kb * 8];
        #pragma unroll
        for (int j = 0; j < 4; ++j) {
            bf16x8 b = *(const bf16x8*)&Bs[j * 16 + lm][kb * 8];
            acc[j] = __builtin_amdgcn_mfma_f32_16x16x32_bf16(a, b, acc[j], 0, 0, 0);
        }
        __syncthreads();
    }

    // C/D layout: col = lane&15 (n), row = (lane>>4)*4 + reg (m)
    const int mrow = m0 + w * 16 + kb * 4;
    #pragma unroll
    for (int j = 0; j < 4; ++j) {
        int n = n0 + j * 16 + lm;
        #pragma unroll
        for (int rg = 0; rg < 4; ++rg)
            Cpart[((size_t)z * SBN + mrow + rg) * HD + n] = acc[j][rg];
    }
}

// ---------------------------------------------------------------------------
// Fused MLP: h = relu(sum_z Cpart * inv_den + b1); hidden (bf16, K-contiguous
// WhidT rows, 16B vector loads); heads. 256 blocks x 512 threads, 1 image.
__global__ __launch_bounds__(512) void mlp_fused(
    const float* __restrict__ Cpart, const float* __restrict__ inv_denom,
    const float* __restrict__ b1, const ushort* __restrict__ WhidT,
    const float* __restrict__ bm1, const float* __restrict__ bs1,
    const float* __restrict__ Wm2, const float* __restrict__ bm2,
    const float* __restrict__ Ws2, const float* __restrict__ bs2,
    const float* __restrict__ eps, float* __restrict__ out,
    float* __restrict__ z_cur, int k)
{
    __shared__ float hsh[HD];
    __shared__ float h2[2][256];       // [head][col]
    __shared__ float res_sh[2][2];     // [zd][head]

    const int t = threadIdx.x;
    const int ib = blockIdx.x;

    {
        float s = 0.f;
        #pragma unroll
        for (int z = 0; z < SPLITK; ++z)
            s += Cpart[((size_t)z * SBN + ib) * HD + t];
        hsh[t] = fmaxf(fmaf(s, inv_denom[ib], b1[t]), 0.f);
    }
    __syncthreads();

    {
        int head = t >> 8, col = t & 255;
        const uint4* Wr = (const uint4*)(WhidT + (size_t)(head * 256 + col) * 512);
        float bias = head ? bs1[col] : bm1[col];
        float a = 0.f;
        #pragma unroll 8
        for (int u = 0; u < 64; ++u) {
            uint4 wv = Wr[u];
            const float* hp = &hsh[u * 8];
            a = fmaf(hp[0], bf2f_lo(wv.x), a);
            a = fmaf(hp[1], bf2f_hi(wv.x), a);
            a = fmaf(hp[2], bf2f_lo(wv.y), a);
            a = fmaf(hp[3], bf2f_hi(wv.y), a);
            a = fmaf(hp[4], bf2f_lo(wv.z), a);
            a = fmaf(hp[5], bf2f_hi(wv.z), a);
            a = fmaf(hp[6], bf2f_lo(wv.w), a);
            a = fmaf(hp[7], bf2f_hi(wv.w), a);
        }
        h2[head][col] = fmaxf(a + bias, 0.f);
    }
    __syncthreads();

    {
        int w = t >> 6, l = t & 63;
        if (w < 4) {
            int zd = (w >> 1) & 1, head = w & 1;
            const float* W2 = head ? Ws2 : Wm2;
            float a = 0.f;
            #pragma unroll
            for (int u = 0; u < 4; ++u) {
                int i = l + u * 64;
                a = fmaf(h2[head][i], W2[i * 2 + zd], a);
            }
            #pragma unroll
            for (int off = 32; off > 0; off >>= 1) a += __shfl_down(a, off, 64);
            if (l == 0) {
                float r = head ? __expf(a + bs2[zd]) : tanhf(a + bm2[zd]);
                res_sh[zd][head] = r;
            }
        }
    }
    __syncthreads();
    if (t < 2) {
        int zd = t;
        float mean = res_sh[zd][0];
        float stdv = res_sh[zd][1];
        float ev = eps[(size_t)ib * 6 + k * 2 + zd];
        float z = fmaf(stdv, ev, mean);
        int oidx = ib * 6 + k * 2 + zd;
        out[oidx]        = mean;   // q_mean
        out[1536 + oidx] = stdv;   // q_std
        out[3072 + oidx] = z;      // z_where
        z_cur[ib * 2 + zd] = z;
    }
}

// ---------------------------------------------------------------------------
extern "C" void kernel_launch(void* const* d_in, const int* in_sizes, int n_in,
                              void* d_out, int out_size, void* d_ws, size_t ws_size,
                              hipStream_t stream)
{
    const float* frames = (const float*)d_in[0];
    const float* ck     = (const float*)d_in[1];
    const float* eps    = (const float*)d_in[2];
    const float* W1     = (const float*)d_in[3];
    const float* b1     = (const float*)d_in[4];
    const float* Wm1    = (const float*)d_in[5];
    const float* bm1    = (const float*)d_in[6];
    const float* Wm2    = (const float*)d_in[7];
    const float* bm2    = (const float*)d_in[8];
    const float* Ws1    = (const float*)d_in[9];
    const float* bs1    = (const float*)d_in[10];
    const float* Ws2    = (const float*)d_in[11];
    const float* bs2    = (const float*)d_in[12];
    const int*   tsp    = (const int*)d_in[13];
    float* out = (float*)d_out;

    float* frameL  = (float*)d_ws;                   // 2359296 f
    float* Cpart   = frameL + 2359296;               // 15*256*512 = 1966080 f
    float* inv_den = Cpart + 1966080;                // 256 f
    float* z_cur   = inv_den + 256;                  // 512 f
    ushort* e_buf  = (ushort*)(z_cur + 512);         // 256*KPAD
    ushort* W1T    = e_buf + (size_t)SBN * KPAD;     // 512*KPAD
    ushort* WhidT  = W1T + (size_t)HD * KPAD;        // 512*512

    wprep_kernel<<<664, 256, 0, stream>>>(W1, Wm1, Ws1, W1T, WhidT);

    for (int k = 0; k < KKC; ++k) {
        conv_softmax_kernel<<<256, 1024, 0, stream>>>(
            frames, tsp, frameL, ck, z_cur, e_buf, inv_den, k);
        gemm1_mfma<<<dim3(4, 8, SPLITK), 256, 0, stream>>>(e_buf, W1T, Cpart);
        mlp_fused<<<256, 512, 0, stream>>>(Cpart, inv_den, b1, WhidT,
                                           bm1, bs1, Wm2, bm2, Ws2, bs2,
                                           eps, out, z_cur, k);
    }
}